// Round 8
// baseline (444.908 us; speedup 1.0000x reference)
//
#include <hip/hip_runtime.h>

static constexpr float SCALE = 0.08838834764831845f; // 1/sqrt(128)

typedef __bf16 bf16;
typedef __bf16 bf16x8 __attribute__((ext_vector_type(8)));
typedef __bf16 bf16x4 __attribute__((ext_vector_type(4)));
typedef float  f32x4  __attribute__((ext_vector_type(4)));

#define MFMA16(a, b, c) __builtin_amdgcn_mfma_f32_16x16x32_bf16((a), (b), (c), 0, 0, 0)

__device__ inline bf16x8 cvt8(const float4& x, const float4& y) {
  bf16x8 r;
  r[0] = (bf16)x.x; r[1] = (bf16)x.y; r[2] = (bf16)x.z; r[3] = (bf16)x.w;
  r[4] = (bf16)y.x; r[5] = (bf16)y.y; r[6] = (bf16)y.z; r[7] = (bf16)y.w;
  return r;
}

// =====================================================================
// Batched projection GEMM (q,k,v in one launch; blockIdx.y selects).
// sel==0 (q): fp32 qf + bf16 q16 in [b,h,i,dk]
// sel==1 (k): bf16 k16 in [b,h,i,dk]
// sel==2 (v): bf16 v16 in [b,h,i,dk]   (plain layout, no transpose)
// =====================================================================
__global__ __launch_bounds__(256)
void proj3_mfma(const float* __restrict__ Aq, const float* __restrict__ Ak,
                const float* __restrict__ Av,
                const float* __restrict__ Wq, const float* __restrict__ Wk,
                const float* __restrict__ Wv,
                const float* __restrict__ bq, const float* __restrict__ bk,
                const float* __restrict__ bv,
                float* __restrict__ qf, bf16* __restrict__ q16,
                bf16* __restrict__ k16, bf16* __restrict__ v16)
{
  const int sel = blockIdx.y;
  const float* A    = sel == 0 ? Aq : (sel == 1 ? Ak : Av);
  const float* W    = sel == 0 ? Wq : (sel == 1 ? Wk : Wv);
  const float* bias = sel == 0 ? bq : (sel == 1 ? bk : bv);
  bf16* Cb          = sel == 0 ? q16 : (sel == 1 ? k16 : v16);

  __shared__ bf16 As[64][72];
  __shared__ bf16 Bs[64][72];
  const int t = threadIdx.x;
  const int m0 = (blockIdx.x >> 4) << 6;
  const int n0 = (blockIdx.x & 15) << 6;
  const int wave = t >> 6, lane = t & 63;
  const int wr = wave >> 1, wc = wave & 1;
  const int srow = t >> 2, skc = (t & 3) << 4;
  const float* Ap = A + (size_t)(m0 + srow) * 1024 + skc;
  const float* Wp = W + (size_t)(n0 + srow) * 1024 + skc;
  const int fr = lane & 15, kb = (lane >> 4) << 3;
  f32x4 acc[2][2];
#pragma unroll
  for (int i = 0; i < 2; ++i)
#pragma unroll
    for (int j = 0; j < 2; ++j) acc[i][j] = (f32x4){0.f, 0.f, 0.f, 0.f};

  float4 a4[4], w4[4], a4n[4], w4n[4];
#pragma unroll
  for (int u = 0; u < 4; ++u) {
    a4[u] = *(const float4*)(Ap + u * 4);
    w4[u] = *(const float4*)(Wp + u * 4);
  }
  for (int k0 = 0; k0 < 1024; k0 += 64) {
    __syncthreads();
    *(bf16x8*)&As[srow][skc]     = cvt8(a4[0], a4[1]);
    *(bf16x8*)&As[srow][skc + 8] = cvt8(a4[2], a4[3]);
    *(bf16x8*)&Bs[srow][skc]     = cvt8(w4[0], w4[1]);
    *(bf16x8*)&Bs[srow][skc + 8] = cvt8(w4[2], w4[3]);
    __syncthreads();
    if (k0 + 64 < 1024) {
#pragma unroll
      for (int u = 0; u < 4; ++u) {
        a4n[u] = *(const float4*)(Ap + k0 + 64 + u * 4);
        w4n[u] = *(const float4*)(Wp + k0 + 64 + u * 4);
      }
    }
#pragma unroll
    for (int ks = 0; ks < 2; ++ks) {
      bf16x8 af[2], bff[2];
#pragma unroll
      for (int f = 0; f < 2; ++f) {
        af[f]  = *(const bf16x8*)&As[wr * 32 + f * 16 + fr][ks * 32 + kb];
        bff[f] = *(const bf16x8*)&Bs[wc * 32 + f * 16 + fr][ks * 32 + kb];
      }
#pragma unroll
      for (int i = 0; i < 2; ++i)
#pragma unroll
        for (int j = 0; j < 2; ++j)
          acc[i][j] = MFMA16(af[i], bff[j], acc[i][j]);
    }
#pragma unroll
    for (int u = 0; u < 4; ++u) { a4[u] = a4n[u]; w4[u] = w4n[u]; }
  }
  const int lrow = (lane >> 4) << 2, lcol = lane & 15;
#pragma unroll
  for (int i = 0; i < 2; ++i) {
#pragma unroll
    for (int j = 0; j < 2; ++j) {
      const int n = n0 + wc * 32 + j * 16 + lcol;
      const float bvl = bias[n];
#pragma unroll
      for (int r = 0; r < 4; ++r) {
        const int m = m0 + wr * 32 + i * 16 + lrow + r;
        const float val = acc[i][j][r] + bvl;
        const int b = m >> 9, ii = m & 511, h = n >> 7, dk = n & 127;
        const size_t idx = (((size_t)(b * 8 + h) * 512) + ii) * 128 + dk;
        Cb[idx] = (bf16)val;
        if (sel == 0) qf[idx] = val;
      }
    }
  }
}

// =====================================================================
// qs_fat: blocks 0..1023 = QK^T MFMA (sc = q16 @ k16^T, overwrite);
//         block 1024     = sep/gating/loss.
// =====================================================================
__global__ __launch_bounds__(256)
void qs_fat(const bf16* __restrict__ Q, const bf16* __restrict__ Kb,
            float* __restrict__ scores,
            const float* __restrict__ qf, const float* __restrict__ hw,
            const int* __restrict__ sep_id, const float* __restrict__ hreg,
            float* __restrict__ g, float* __restrict__ loss_out)
{
  __shared__ bf16 As[64][72];
  __shared__ bf16 Bs[64][72];
  __shared__ float pool[16][4];
  __shared__ float spred[16][4];
  __shared__ float lbuf[16];
  __shared__ int sids[4];
  const int t = threadIdx.x;

  if (blockIdx.x >= 1024) {
    if (t < 4) sids[t] = sep_id[t];
    __syncthreads();
    {
      const int dot = t >> 2, sub = t & 3;
      const int bh = dot >> 2, n = dot & 3;
      const int b = bh >> 3, h = bh & 7;
      const int row = sids[n];
      const float* qp = qf + (((size_t)(b * 8 + h) * 512) + row) * 128 + sub * 32;
      const float* wp = hw + h * 128 + sub * 32;
      float s = 0.f;
#pragma unroll
      for (int dd = 0; dd < 32; ++dd) s = fmaf(qp[dd], wp[dd], s);
      s += __shfl_xor(s, 1);
      s += __shfl_xor(s, 2);
      if (sub == 0) pool[bh][n] = s;
    }
    __syncthreads();
    if (t < 16) {
      float pv[4];
#pragma unroll
      for (int n = 0; n < 4; ++n) pv[n] = pool[t][n];
      float mx = fmaxf(fmaxf(pv[0], pv[1]), fmaxf(pv[2], pv[3]));
      float sum = 0.f;
#pragma unroll
      for (int n = 0; n < 4; ++n) { pv[n] = expf(pv[n] - mx); sum += pv[n]; }
      const float inv = 1.f / sum;
      float maxp = 0.f, l2 = 0.f;
#pragma unroll
      for (int n = 0; n < 4; ++n) {
        const float pr = pv[n] * inv;
        spred[t][n] = pr;
        maxp = fmaxf(maxp, pr);
        const float tg = hreg[n];
        l2 += tg * (logf(tg) - logf(pr));
      }
      lbuf[t] = (1.f - maxp) / 16.f + l2 / 64.f;
    }
    __syncthreads();
    if (t == 0) {
      float L = 0.f;
#pragma unroll
      for (int r = 0; r < 16; ++r) L += lbuf[r];
      loss_out[0] = L;
    }
    for (int idx = t; idx < 16 * 512; idx += 256) {
      const int bh = idx >> 9, pp = idx & 511;
      float gg = 0.f;
#pragma unroll
      for (int n = 0; n < 4; ++n)
        gg += spred[bh][n] * (pp >= sids[n] ? 1.f : 0.f);
      g[idx] = gg;
    }
    return;
  }

  const int bh = blockIdx.x >> 6, tile = blockIdx.x & 63;
  const bf16* A = Q  + (size_t)bh * (512 * 128);
  const bf16* B = Kb + (size_t)bh * (512 * 128);
  float* C = scores + (size_t)bh * (512 * 512);
  const int m0 = (tile >> 3) << 6, n0 = (tile & 7) << 6;
  const int wave = t >> 6, lane = t & 63;
  const int wr = wave >> 1, wc = wave & 1;
  const int srow = t >> 2, skc = (t & 3) << 4;
  const int fr = lane & 15, kb = (lane >> 4) << 3;
  f32x4 acc[2][2];
#pragma unroll
  for (int i = 0; i < 2; ++i)
#pragma unroll
    for (int j = 0; j < 2; ++j) acc[i][j] = (f32x4){0.f, 0.f, 0.f, 0.f};

  const bf16* ap = A + (size_t)(m0 + srow) * 128 + skc;
  const bf16* bp = B + (size_t)(n0 + srow) * 128 + skc;
  uint4 a0 = *(const uint4*)ap, a1 = *(const uint4*)(ap + 8);
  uint4 b0 = *(const uint4*)bp, b1 = *(const uint4*)(bp + 8);
  for (int k0 = 0; k0 < 128; k0 += 64) {
    __syncthreads();
    *(uint4*)&As[srow][skc]     = a0; *(uint4*)&As[srow][skc + 8] = a1;
    *(uint4*)&Bs[srow][skc]     = b0; *(uint4*)&Bs[srow][skc + 8] = b1;
    __syncthreads();
    if (k0 == 0) {
      a0 = *(const uint4*)(ap + 64); a1 = *(const uint4*)(ap + 72);
      b0 = *(const uint4*)(bp + 64); b1 = *(const uint4*)(bp + 72);
    }
#pragma unroll
    for (int ks = 0; ks < 2; ++ks) {
      bf16x8 af[2], bff[2];
#pragma unroll
      for (int f = 0; f < 2; ++f) {
        af[f]  = *(const bf16x8*)&As[wr * 32 + f * 16 + fr][ks * 32 + kb];
        bff[f] = *(const bf16x8*)&Bs[wc * 32 + f * 16 + fr][ks * 32 + kb];
      }
#pragma unroll
      for (int i = 0; i < 2; ++i)
#pragma unroll
        for (int j = 0; j < 2; ++j)
          acc[i][j] = MFMA16(af[i], bff[j], acc[i][j]);
    }
  }
  const int lrow = (lane >> 4) << 2, lcol = lane & 15;
#pragma unroll
  for (int i = 0; i < 2; ++i)
#pragma unroll
    for (int j = 0; j < 2; ++j)
#pragma unroll
      for (int r = 0; r < 4; ++r) {
        const int m = m0 + wr * 32 + i * 16 + lrow + r;
        const int n = n0 + wc * 32 + j * 16 + lcol;
        C[(size_t)m * 512 + n] = acc[i][j][r];
      }
}

// =====================================================================
// stream_attn2: one block per (b,i). 37.5 KB LDS, phases:
//  0: q row -> LDS
//  1: stream rk -> rel[h][j]  (R6 single-j version, low VGPR)
//  2: softmax((sc+rel)*SCALE, mask, factor) IN PLACE (rel := p, fp32)
//  3a: stream rv; acc3[h] += p[h,j]*rv[j,d]   (j-groups, rv read once)
//  3b: stream v16[b,h]; accv += p[h,j]*v[h,j,d] (one h per 32-lane group,
//      contiguous 256B/j rows, v16 is L2-resident)
//  4: cross-group reduce acc3 via LDS, add accv, write bf16 x.
// =====================================================================
__global__ __launch_bounds__(256)
void stream_attn2(const float* __restrict__ qf, const float* __restrict__ rk,
                  const float* __restrict__ sc, const int* __restrict__ mask,
                  const float* __restrict__ g, const float* __restrict__ rv,
                  const bf16* __restrict__ v16, bf16* __restrict__ x16)
{
  const int bi = blockIdx.x, b = bi >> 9, i = bi & 511;
  __shared__ float smem[9376];          // 37.5 KB
  float* qs_  = smem;                   // [8][144]  phase 0-1
  float* rel_ = smem + 1152;            // [8][516]  phase 1-3 (p after sm)
  float* red_ = smem + 5280;            // [4][8][128] phase 4
  const int t = threadIdx.x;

  // phase 0
  {
    const int h = t >> 5, d0 = (t & 31) << 2;
    const int sub2 = d0 >> 5, dd = d0 & 31;
    const float4 qv = *(const float4*)&qf[(((size_t)(b * 8 + h) * 512) + i) * 128 + d0];
    *(float4*)&qs_[h * 144 + sub2 * 36 + dd] = qv;
  }
  __syncthreads();

  // phase 1: rel[h][j] = q[h].rk[j]
  const int jj = t >> 2, sub = t & 3;
  for (int jp = 0; jp < 512; jp += 64) {
    const int j = jp + jj;
    const float* rkp = rk + ((size_t)bi * 512 + j) * 128 + sub * 32;
    float rvl[32];
#pragma unroll
    for (int u = 0; u < 8; ++u)
      *(float4*)&rvl[u * 4] = *(const float4*)&rkp[u * 4];
    float acc[8];
#pragma unroll
    for (int h = 0; h < 8; ++h) acc[h] = 0.f;
#pragma unroll
    for (int d4 = 0; d4 < 8; ++d4) {
#pragma unroll
      for (int h = 0; h < 8; ++h) {
        const float4 qv = *(const float4*)&qs_[h * 144 + sub * 36 + (d4 << 2)];
        acc[h] = fmaf(qv.x, rvl[d4*4+0], acc[h]);
        acc[h] = fmaf(qv.y, rvl[d4*4+1], acc[h]);
        acc[h] = fmaf(qv.z, rvl[d4*4+2], acc[h]);
        acc[h] = fmaf(qv.w, rvl[d4*4+3], acc[h]);
      }
    }
#pragma unroll
    for (int h = 0; h < 8; ++h) {
      acc[h] += __shfl_xor(acc[h], 1);
      acc[h] += __shfl_xor(acc[h], 2);
    }
    const int h0 = sub << 1;
    rel_[h0 * 516 + j]       = acc[h0];
    rel_[(h0 + 1) * 516 + j] = acc[h0 + 1];
  }
  __syncthreads();

  // phase 2: softmax in place (each thread owns its (h, j=ln+32k) slots)
  {
    const int h = t >> 5, ln = t & 31;
    const float* scrow = sc + (((size_t)(b * 8 + h) * 512) + i) * 512;
    const int* mrow = mask + ((size_t)(b * 512 + i)) * 512;
    const float* grow = g + (b * 8 + h) * 512;
    const float gi = grow[i];
    float s[16];
    float mx = -3.402823466e+38f;
#pragma unroll
    for (int k = 0; k < 16; ++k) {
      const int j = ln + (k << 5);
      float sv = (scrow[j] + rel_[h * 516 + j]) * SCALE;
      if (mrow[j] == 0) sv = -1.0e9f;
      const float fac = (j >= i) ? gi : grow[j];
      sv *= fac;
      s[k] = sv;
      mx = fmaxf(mx, sv);
    }
#pragma unroll
    for (int off = 16; off > 0; off >>= 1) mx = fmaxf(mx, __shfl_xor(mx, off));
    float sum = 0.f;
#pragma unroll
    for (int k = 0; k < 16; ++k) { const float e = __expf(s[k] - mx); s[k] = e; sum += e; }
#pragma unroll
    for (int off = 16; off > 0; off >>= 1) sum += __shfl_xor(sum, off);
    const float inv = 1.f / sum;
#pragma unroll
    for (int k = 0; k < 16; ++k) rel_[h * 516 + ln + (k << 5)] = s[k] * inv;
  }
  __syncthreads();

  // phase 3a: rv stream (group gq covers j = gq, gq+8, ...)
  const int gq = t >> 5, ln3 = t & 31, d0 = ln3 << 2;
  f32x4 acc3[8];
#pragma unroll
  for (int h = 0; h < 8; ++h) acc3[h] = (f32x4){0.f, 0.f, 0.f, 0.f};
  const float* rp = rv + (size_t)bi * 512 * 128 + d0;
  for (int j = gq; j < 512; j += 8) {
    const float4 rr = *(const float4*)&rp[(size_t)j * 128];
#pragma unroll
    for (int h = 0; h < 8; ++h) {
      const float w = rel_[h * 516 + j];
      acc3[h][0] = fmaf(w, rr.x, acc3[h][0]);
      acc3[h][1] = fmaf(w, rr.y, acc3[h][1]);
      acc3[h][2] = fmaf(w, rr.z, acc3[h][2]);
      acc3[h][3] = fmaf(w, rr.w, acc3[h][3]);
    }
  }

  // phase 3b: PV — group handles head h = gq, all j, dims d0..d0+3
  f32x4 accv = (f32x4){0.f, 0.f, 0.f, 0.f};
  {
    const bf16* vp = v16 + (((size_t)(b * 8 + gq) * 512)) * 128 + d0;
    const float* prow = &rel_[gq * 516];
#pragma unroll 4
    for (int j = 0; j < 512; ++j) {
      const bf16x4 vv = *(const bf16x4*)(vp + (size_t)j * 128);
      const float w = prow[j];
      accv[0] = fmaf(w, (float)vv[0], accv[0]);
      accv[1] = fmaf(w, (float)vv[1], accv[1]);
      accv[2] = fmaf(w, (float)vv[2], accv[2]);
      accv[3] = fmaf(w, (float)vv[3], accv[3]);
    }
  }

  // phase 4: reduce acc3 across groups, add accv, write bf16
#pragma unroll
  for (int h = 0; h < 8; ++h)
#pragma unroll
    for (int e = 0; e < 4; ++e) acc3[h][e] += __shfl_xor(acc3[h][e], 32);
  const int wv = t >> 6;
  if ((t & 63) < 32) {
#pragma unroll
    for (int h = 0; h < 8; ++h)
      *(f32x4*)&red_[(wv * 8 + h) * 128 + d0] = acc3[h];
  }
  __syncthreads();
  {
    const int h = t >> 5, dd = (t & 31) << 2;   // same mapping as (gq, d0)
    f32x4 r = accv;
#pragma unroll
    for (int w2 = 0; w2 < 4; ++w2) {
      const f32x4 v = *(const f32x4*)&red_[(w2 * 8 + h) * 128 + dd];
      r[0] += v[0]; r[1] += v[1]; r[2] += v[2]; r[3] += v[3];
    }
    bf16x4 o;
#pragma unroll
    for (int e = 0; e < 4; ++e) o[e] = (bf16)r[e];
    *(bf16x4*)&x16[((size_t)(b * 512 + i)) * 1024 + h * 128 + dd] = o;
  }
}

// =====================================================================
// Output projection: Cf[m*1024+n] = A(bf16) @ W^T + bias
// =====================================================================
__global__ __launch_bounds__(256)
void proj_out(const bf16* __restrict__ A, const float* __restrict__ W,
              const float* __restrict__ bias, float* __restrict__ Cf)
{
  __shared__ bf16 As[64][72];
  __shared__ bf16 Bs[64][72];
  const int t = threadIdx.x;
  const int m0 = (blockIdx.x >> 4) << 6;
  const int n0 = (blockIdx.x & 15) << 6;
  const int wave = t >> 6, lane = t & 63;
  const int wr = wave >> 1, wc = wave & 1;
  const int srow = t >> 2, skc = (t & 3) << 4;
  const bf16*  Ap = A + (size_t)(m0 + srow) * 1024 + skc;
  const float* Wp = W + (size_t)(n0 + srow) * 1024 + skc;
  const int fr = lane & 15, kb = (lane >> 4) << 3;
  f32x4 acc[2][2];
#pragma unroll
  for (int i = 0; i < 2; ++i)
#pragma unroll
    for (int j = 0; j < 2; ++j) acc[i][j] = (f32x4){0.f, 0.f, 0.f, 0.f};

  uint4 a0 = *(const uint4*)Ap, a1 = *(const uint4*)(Ap + 8);
  float4 w4[4], w4n[4];
  uint4 a0n, a1n;
#pragma unroll
  for (int u = 0; u < 4; ++u) w4[u] = *(const float4*)(Wp + u * 4);
  for (int k0 = 0; k0 < 1024; k0 += 64) {
    __syncthreads();
    *(uint4*)&As[srow][skc]      = a0;
    *(uint4*)&As[srow][skc + 8]  = a1;
    *(bf16x8*)&Bs[srow][skc]     = cvt8(w4[0], w4[1]);
    *(bf16x8*)&Bs[srow][skc + 8] = cvt8(w4[2], w4[3]);
    __syncthreads();
    if (k0 + 64 < 1024) {
      a0n = *(const uint4*)(Ap + k0 + 64);
      a1n = *(const uint4*)(Ap + k0 + 72);
#pragma unroll
      for (int u = 0; u < 4; ++u)
        w4n[u] = *(const float4*)(Wp + k0 + 64 + u * 4);
    }
#pragma unroll
    for (int ks = 0; ks < 2; ++ks) {
      bf16x8 af[2], bff[2];
#pragma unroll
      for (int f = 0; f < 2; ++f) {
        af[f]  = *(const bf16x8*)&As[wr * 32 + f * 16 + fr][ks * 32 + kb];
        bff[f] = *(const bf16x8*)&Bs[wc * 32 + f * 16 + fr][ks * 32 + kb];
      }
#pragma unroll
      for (int i = 0; i < 2; ++i)
#pragma unroll
        for (int j = 0; j < 2; ++j)
          acc[i][j] = MFMA16(af[i], bff[j], acc[i][j]);
    }
    a0 = a0n; a1 = a1n;
#pragma unroll
    for (int u = 0; u < 4; ++u) w4[u] = w4n[u];
  }
  const int lrow = (lane >> 4) << 2, lcol = lane & 15;
#pragma unroll
  for (int i = 0; i < 2; ++i) {
#pragma unroll
    for (int j = 0; j < 2; ++j) {
      const int n = n0 + wc * 32 + j * 16 + lcol;
      const float bvl = bias[n];
#pragma unroll
      for (int r = 0; r < 4; ++r) {
        const int m = m0 + wr * 32 + i * 16 + lrow + r;
        Cf[(size_t)m * 1024 + n] = acc[i][j][r] + bvl;
      }
    }
  }
}

// =====================================================================
extern "C" void kernel_launch(void* const* d_in, const int* in_sizes, int n_in,
                              void* d_out, int out_size, void* d_ws, size_t ws_size,
                              hipStream_t stream)
{
  const float* query = (const float*)d_in[0];
  const float* key   = (const float*)d_in[1];
  const float* value = (const float*)d_in[2];
  const float* rk    = (const float*)d_in[3];
  const float* rv    = (const float*)d_in[4];
  const int*   mask  = (const int*)d_in[5];
  const int*   sep   = (const int*)d_in[6];
  const float* hreg  = (const float*)d_in[7];
  const float* Wq    = (const float*)d_in[8];
  const float* bq    = (const float*)d_in[9];
  const float* Wk    = (const float*)d_in[10];
  const float* bk    = (const float*)d_in[11];
  const float* Wv    = (const float*)d_in[12];
  const float* bv    = (const float*)d_in[13];
  const float* Wo    = (const float*)d_in[14];
  const float* bo    = (const float*)d_in[15];
  const float* hw    = (const float*)d_in[16];
  float* out = (float*)d_out;

  float* ws  = (float*)d_ws;
  float* qb  = ws;                           // 1,048,576 f32
  float* sc  = qb + 1048576;                 // 4,194,304 f32
  float* gb  = sc + 4194304;                 //     8,192 f32
  bf16* qb16 = (bf16*)(gb + 8192);           // 1,048,576 bf16
  bf16* kb16 = qb16 + 1048576;               // 1,048,576 bf16
  bf16* v16  = kb16 + 1048576;               // 1,048,576 bf16
  bf16* x16  = v16 + 1048576;                // 1,048,576 bf16

  proj3_mfma<<<dim3(256, 3), 256, 0, stream>>>(query, key, value,
                                               Wq, Wk, Wv, bq, bk, bv,
                                               qb, qb16, kb16, v16);
  qs_fat<<<dim3(1025), 256, 0, stream>>>(qb16, kb16, sc,
                                         qb, hw, sep, hreg, gb, out + 1048576);
  stream_attn2<<<dim3(1024), 256, 0, stream>>>(qb, rk, sc, mask, gb, rv,
                                               v16, x16);
  proj_out<<<dim3(256), 256, 0, stream>>>(x16, Wo, bo, out);
}

// Round 9
// 188.627 us; speedup vs baseline: 2.3587x; 2.3587x over previous
//
#include <hip/hip_runtime.h>

static constexpr float SCALE = 0.08838834764831845f; // 1/sqrt(128)

typedef __bf16 bf16;
typedef __bf16 bf16x8 __attribute__((ext_vector_type(8)));
typedef float  f32x4  __attribute__((ext_vector_type(4)));

#define MFMA16(a, b, c) __builtin_amdgcn_mfma_f32_16x16x32_bf16((a), (b), (c), 0, 0, 0)

__device__ inline bf16x8 cvt8(const float4& x, const float4& y) {
  bf16x8 r;
  r[0] = (bf16)x.x; r[1] = (bf16)x.y; r[2] = (bf16)x.z; r[3] = (bf16)x.w;
  r[4] = (bf16)y.x; r[5] = (bf16)y.y; r[6] = (bf16)y.z; r[7] = (bf16)y.w;
  return r;
}

// =====================================================================
// Batched projection GEMM (q,k,v in one launch; blockIdx.y selects).
// sel==0 (q): fp32 qf + bf16 q16 in [b,h,i,dk]
// sel==1 (k): bf16 k16 in [b,h,i,dk]
// sel==2 (v): bf16 vt16 TRANSPOSED [b,h,dk,i]
// =====================================================================
__global__ __launch_bounds__(256)
void proj3_mfma(const float* __restrict__ Aq, const float* __restrict__ Ak,
                const float* __restrict__ Av,
                const float* __restrict__ Wq, const float* __restrict__ Wk,
                const float* __restrict__ Wv,
                const float* __restrict__ bq, const float* __restrict__ bk,
                const float* __restrict__ bv,
                float* __restrict__ qf, bf16* __restrict__ q16,
                bf16* __restrict__ k16, bf16* __restrict__ vt16)
{
  const int sel = blockIdx.y;
  const float* A    = sel == 0 ? Aq : (sel == 1 ? Ak : Av);
  const float* W    = sel == 0 ? Wq : (sel == 1 ? Wk : Wv);
  const float* bias = sel == 0 ? bq : (sel == 1 ? bk : bv);

  __shared__ bf16 As[64][72];
  __shared__ bf16 Bs[64][72];
  const int t = threadIdx.x;
  const int m0 = (blockIdx.x >> 4) << 6;
  const int n0 = (blockIdx.x & 15) << 6;
  const int wave = t >> 6, lane = t & 63;
  const int wr = wave >> 1, wc = wave & 1;
  const int srow = t >> 2, skc = (t & 3) << 4;
  const float* Ap = A + (size_t)(m0 + srow) * 1024 + skc;
  const float* Wp = W + (size_t)(n0 + srow) * 1024 + skc;
  const int fr = lane & 15, kb = (lane >> 4) << 3;
  f32x4 acc[2][2];
#pragma unroll
  for (int i = 0; i < 2; ++i)
#pragma unroll
    for (int j = 0; j < 2; ++j) acc[i][j] = (f32x4){0.f, 0.f, 0.f, 0.f};

  float4 a4[4], w4[4], a4n[4], w4n[4];
#pragma unroll
  for (int u = 0; u < 4; ++u) {
    a4[u] = *(const float4*)(Ap + u * 4);
    w4[u] = *(const float4*)(Wp + u * 4);
  }
  for (int k0 = 0; k0 < 1024; k0 += 64) {
    __syncthreads();
    *(bf16x8*)&As[srow][skc]     = cvt8(a4[0], a4[1]);
    *(bf16x8*)&As[srow][skc + 8] = cvt8(a4[2], a4[3]);
    *(bf16x8*)&Bs[srow][skc]     = cvt8(w4[0], w4[1]);
    *(bf16x8*)&Bs[srow][skc + 8] = cvt8(w4[2], w4[3]);
    __syncthreads();
    if (k0 + 64 < 1024) {
#pragma unroll
      for (int u = 0; u < 4; ++u) {
        a4n[u] = *(const float4*)(Ap + k0 + 64 + u * 4);
        w4n[u] = *(const float4*)(Wp + k0 + 64 + u * 4);
      }
    }
#pragma unroll
    for (int ks = 0; ks < 2; ++ks) {
      bf16x8 af[2], bff[2];
#pragma unroll
      for (int f = 0; f < 2; ++f) {
        af[f]  = *(const bf16x8*)&As[wr * 32 + f * 16 + fr][ks * 32 + kb];
        bff[f] = *(const bf16x8*)&Bs[wc * 32 + f * 16 + fr][ks * 32 + kb];
      }
#pragma unroll
      for (int i = 0; i < 2; ++i)
#pragma unroll
        for (int j = 0; j < 2; ++j)
          acc[i][j] = MFMA16(af[i], bff[j], acc[i][j]);
    }
#pragma unroll
    for (int u = 0; u < 4; ++u) { a4[u] = a4n[u]; w4[u] = w4n[u]; }
  }
  const int lrow = (lane >> 4) << 2, lcol = lane & 15;
#pragma unroll
  for (int i = 0; i < 2; ++i) {
#pragma unroll
    for (int j = 0; j < 2; ++j) {
      const int n = n0 + wc * 32 + j * 16 + lcol;
      const float bvl = bias[n];
#pragma unroll
      for (int r = 0; r < 4; ++r) {
        const int m = m0 + wr * 32 + i * 16 + lrow + r;
        const float val = acc[i][j][r] + bvl;
        const int b = m >> 9, ii = m & 511, h = n >> 7, dk = n & 127;
        if (sel == 2) {
          vt16[(((size_t)(b * 8 + h) * 128) + dk) * 512 + ii] = (bf16)val;
        } else {
          const size_t idx = (((size_t)(b * 8 + h) * 512) + ii) * 128 + dk;
          if (sel == 0) { qf[idx] = val; q16[idx] = (bf16)val; }
          else          { k16[idx] = (bf16)val; }
        }
      }
    }
  }
}

// =====================================================================
// qs_fat: blocks 0..1023 = QK^T MFMA (sc = q16 @ k16^T, overwrite);
//         block 1024     = sep/gating/loss.
// =====================================================================
__global__ __launch_bounds__(256)
void qs_fat(const bf16* __restrict__ Q, const bf16* __restrict__ Kb,
            float* __restrict__ scores,
            const float* __restrict__ qf, const float* __restrict__ hw,
            const int* __restrict__ sep_id, const float* __restrict__ hreg,
            float* __restrict__ g, float* __restrict__ loss_out)
{
  __shared__ bf16 As[64][72];
  __shared__ bf16 Bs[64][72];
  __shared__ float pool[16][4];
  __shared__ float spred[16][4];
  __shared__ float lbuf[16];
  __shared__ int sids[4];
  const int t = threadIdx.x;

  if (blockIdx.x >= 1024) {
    if (t < 4) sids[t] = sep_id[t];
    __syncthreads();
    {
      const int dot = t >> 2, sub = t & 3;
      const int bh = dot >> 2, n = dot & 3;
      const int b = bh >> 3, h = bh & 7;
      const int row = sids[n];
      const float* qp = qf + (((size_t)(b * 8 + h) * 512) + row) * 128 + sub * 32;
      const float* wp = hw + h * 128 + sub * 32;
      float s = 0.f;
#pragma unroll
      for (int dd = 0; dd < 32; ++dd) s = fmaf(qp[dd], wp[dd], s);
      s += __shfl_xor(s, 1);
      s += __shfl_xor(s, 2);
      if (sub == 0) pool[bh][n] = s;
    }
    __syncthreads();
    if (t < 16) {
      float pv[4];
#pragma unroll
      for (int n = 0; n < 4; ++n) pv[n] = pool[t][n];
      float mx = fmaxf(fmaxf(pv[0], pv[1]), fmaxf(pv[2], pv[3]));
      float sum = 0.f;
#pragma unroll
      for (int n = 0; n < 4; ++n) { pv[n] = expf(pv[n] - mx); sum += pv[n]; }
      const float inv = 1.f / sum;
      float maxp = 0.f, l2 = 0.f;
#pragma unroll
      for (int n = 0; n < 4; ++n) {
        const float pr = pv[n] * inv;
        spred[t][n] = pr;
        maxp = fmaxf(maxp, pr);
        const float tg = hreg[n];
        l2 += tg * (logf(tg) - logf(pr));
      }
      lbuf[t] = (1.f - maxp) / 16.f + l2 / 64.f;
    }
    __syncthreads();
    if (t == 0) {
      float L = 0.f;
#pragma unroll
      for (int r = 0; r < 16; ++r) L += lbuf[r];
      loss_out[0] = L;
    }
    for (int idx = t; idx < 16 * 512; idx += 256) {
      const int bh = idx >> 9, pp = idx & 511;
      float gg = 0.f;
#pragma unroll
      for (int n = 0; n < 4; ++n)
        gg += spred[bh][n] * (pp >= sids[n] ? 1.f : 0.f);
      g[idx] = gg;
    }
    return;
  }

  const int bh = blockIdx.x >> 6, tile = blockIdx.x & 63;
  const bf16* A = Q  + (size_t)bh * (512 * 128);
  const bf16* B = Kb + (size_t)bh * (512 * 128);
  float* C = scores + (size_t)bh * (512 * 512);
  const int m0 = (tile >> 3) << 6, n0 = (tile & 7) << 6;
  const int wave = t >> 6, lane = t & 63;
  const int wr = wave >> 1, wc = wave & 1;
  const int srow = t >> 2, skc = (t & 3) << 4;
  const int fr = lane & 15, kb = (lane >> 4) << 3;
  f32x4 acc[2][2];
#pragma unroll
  for (int i = 0; i < 2; ++i)
#pragma unroll
    for (int j = 0; j < 2; ++j) acc[i][j] = (f32x4){0.f, 0.f, 0.f, 0.f};

  const bf16* ap = A + (size_t)(m0 + srow) * 128 + skc;
  const bf16* bp = B + (size_t)(n0 + srow) * 128 + skc;
  uint4 a0 = *(const uint4*)ap, a1 = *(const uint4*)(ap + 8);
  uint4 b0 = *(const uint4*)bp, b1 = *(const uint4*)(bp + 8);
  for (int k0 = 0; k0 < 128; k0 += 64) {
    __syncthreads();
    *(uint4*)&As[srow][skc]     = a0; *(uint4*)&As[srow][skc + 8] = a1;
    *(uint4*)&Bs[srow][skc]     = b0; *(uint4*)&Bs[srow][skc + 8] = b1;
    __syncthreads();
    if (k0 == 0) {
      a0 = *(const uint4*)(ap + 64); a1 = *(const uint4*)(ap + 72);
      b0 = *(const uint4*)(bp + 64); b1 = *(const uint4*)(bp + 72);
    }
#pragma unroll
    for (int ks = 0; ks < 2; ++ks) {
      bf16x8 af[2], bff[2];
#pragma unroll
      for (int f = 0; f < 2; ++f) {
        af[f]  = *(const bf16x8*)&As[wr * 32 + f * 16 + fr][ks * 32 + kb];
        bff[f] = *(const bf16x8*)&Bs[wc * 32 + f * 16 + fr][ks * 32 + kb];
      }
#pragma unroll
      for (int i = 0; i < 2; ++i)
#pragma unroll
        for (int j = 0; j < 2; ++j)
          acc[i][j] = MFMA16(af[i], bff[j], acc[i][j]);
    }
  }
  const int lrow = (lane >> 4) << 2, lcol = lane & 15;
#pragma unroll
  for (int i = 0; i < 2; ++i)
#pragma unroll
    for (int j = 0; j < 2; ++j)
#pragma unroll
      for (int r = 0; r < 4; ++r) {
        const int m = m0 + wr * 32 + i * 16 + lrow + r;
        const int n = n0 + wc * 32 + j * 16 + lcol;
        C[(size_t)m * 512 + n] = acc[i][j][r];
      }
}

// =====================================================================
// relk_sm: per (b,i) block.
// Phase 1 (MFMA): rel[j,h] = rk[b,i] (512x128) @ q(16x128)^T
//   A-frag: rk rows (streamed, f32->bf16 in regs); B-frag: q rows (regs).
// Phase 2: softmax((sc+rel)*SCALE, mask, factor) -> pb16.
// LDS: rel only (16.5 KB) -> 8 blocks/CU.
// =====================================================================
__global__ __launch_bounds__(256)
void relk_sm(const float* __restrict__ qf, const float* __restrict__ rk,
             const float* __restrict__ sc, const int* __restrict__ mask,
             const float* __restrict__ g, bf16* __restrict__ pb)
{
  const int bi = blockIdx.x, b = bi >> 9, i = bi & 511;
  __shared__ float rel_[8 * 516];
  const int t = threadIdx.x;
  const int w = t >> 6, lane = t & 63;
  const int fr = lane & 15, fg = lane >> 4;

  // B-frags: q[h=fr][k = kt*32 + fg*8 + e], zero for fr >= 8
  bf16x8 bq[4];
#pragma unroll
  for (int kt = 0; kt < 4; ++kt) {
    if (fr < 8) {
      const float* qp = qf + (((size_t)(b * 8 + fr) * 512) + i) * 128 + kt * 32 + fg * 8;
      const float4 q0 = *(const float4*)qp;
      const float4 q1 = *(const float4*)(qp + 4);
      bq[kt] = cvt8(q0, q1);
    } else {
#pragma unroll
      for (int e = 0; e < 8; ++e) bq[kt][e] = (bf16)0.f;
    }
  }

  const float* rkb = rk + (size_t)bi * 512 * 128;
  for (int c = 0; c < 8; ++c) {
    const int jb = c * 64 + w * 16;
    const float* rp = rkb + (size_t)(jb + fr) * 128 + fg * 8;
    float4 a[8];
#pragma unroll
    for (int kt = 0; kt < 4; ++kt) {
      a[kt * 2]     = *(const float4*)(rp + kt * 32);
      a[kt * 2 + 1] = *(const float4*)(rp + kt * 32 + 4);
    }
    f32x4 acc = (f32x4){0.f, 0.f, 0.f, 0.f};
#pragma unroll
    for (int kt = 0; kt < 4; ++kt)
      acc = MFMA16(cvt8(a[kt * 2], a[kt * 2 + 1]), bq[kt], acc);
    // D[m=j_local][n=h]: lane holds rows fg*4+r, col fr
    if (fr < 8) {
#pragma unroll
      for (int r = 0; r < 4; ++r)
        rel_[fr * 516 + jb + fg * 4 + r] = acc[r];
    }
  }
  __syncthreads();

  // phase 2: softmax per head row
  const int h = t >> 5, ln = t & 31;
  const float* scrow = sc + (((size_t)(b * 8 + h) * 512) + i) * 512;
  const int* mrow = mask + ((size_t)(b * 512 + i)) * 512;
  const float* grow = g + (b * 8 + h) * 512;
  const float gi = grow[i];
  float s[16];
  float mx = -3.402823466e+38f;
#pragma unroll
  for (int k = 0; k < 16; ++k) {
    const int j = ln + (k << 5);
    float sv = (scrow[j] + rel_[h * 516 + j]) * SCALE;
    if (mrow[j] == 0) sv = -1.0e9f;
    const float fac = (j >= i) ? gi : grow[j];
    sv *= fac;
    s[k] = sv;
    mx = fmaxf(mx, sv);
  }
#pragma unroll
  for (int off = 16; off > 0; off >>= 1) mx = fmaxf(mx, __shfl_xor(mx, off));
  float sum = 0.f;
#pragma unroll
  for (int k = 0; k < 16; ++k) { const float e = __expf(s[k] - mx); s[k] = e; sum += e; }
#pragma unroll
  for (int off = 16; off > 0; off >>= 1) sum += __shfl_xor(sum, off);
  const float inv = 1.f / sum;
  bf16* prow = pb + (((size_t)(b * 8 + h) * 512) + i) * 512;
#pragma unroll
  for (int k = 0; k < 16; ++k) {
    const int j = ln + (k << 5);
    prow[j] = (bf16)(s[k] * inv);
  }
}

// =====================================================================
// relv_fat:
//  blocks 0..255    = PV MFMA (xb2 = p16 @ vt16, overwrite) [R6 proven]
//  blocks 256..1279 = relv MFMA per (b,i):
//     xa[h,d] = sum_j p[h,j]*rv[j,d]  via p(16x512)@rvT(128x512)
//     rv staged transposed to LDS bf16 with block-rotation swizzle.
// =====================================================================
__global__ __launch_bounds__(256)
void relv_fat(const bf16* __restrict__ P, const bf16* __restrict__ VT,
              const float* __restrict__ rvg,
              float* __restrict__ xb2, float* __restrict__ xa)
{
  __shared__ __align__(16) char smem_raw[26032];
  const int t = threadIdx.x;

  if (blockIdx.x < 256) {
    // ---- PV MFMA (verbatim R6) ----
    bf16 (*As)[72] = (bf16(*)[72])&smem_raw[0];
    bf16 (*Bs)[72] = (bf16(*)[72])&smem_raw[9216];
    const int bh = blockIdx.x >> 4, tile = blockIdx.x & 15;
    const int b = bh >> 3, h = bh & 7;
    const bf16* A = P  + (size_t)bh * (512 * 512);
    const bf16* B = VT + (size_t)bh * (128 * 512);
    float* C = xb2 + (size_t)b * (512 * 1024) + h * 128;
    const int m0 = (tile >> 1) << 6, n0 = (tile & 1) << 6;
    const int wave = t >> 6, lane = t & 63;
    const int wr = wave >> 1, wc = wave & 1;
    const int srow = t >> 2, skc = (t & 3) << 4;
    const int fr = lane & 15, kb = (lane >> 4) << 3;
    f32x4 acc[2][2];
#pragma unroll
    for (int i = 0; i < 2; ++i)
#pragma unroll
      for (int j = 0; j < 2; ++j) acc[i][j] = (f32x4){0.f, 0.f, 0.f, 0.f};

    const bf16* ap = A + (size_t)(m0 + srow) * 512 + skc;
    const bf16* bp = B + (size_t)(n0 + srow) * 512 + skc;
    uint4 a0 = *(const uint4*)ap, a1 = *(const uint4*)(ap + 8);
    uint4 b0 = *(const uint4*)bp, b1 = *(const uint4*)(bp + 8);
    for (int k0 = 0; k0 < 512; k0 += 64) {
      __syncthreads();
      *(uint4*)&As[srow][skc]     = a0; *(uint4*)&As[srow][skc + 8] = a1;
      *(uint4*)&Bs[srow][skc]     = b0; *(uint4*)&Bs[srow][skc + 8] = b1;
      __syncthreads();
      if (k0 + 64 < 512) {
        a0 = *(const uint4*)(ap + k0 + 64); a1 = *(const uint4*)(ap + k0 + 72);
        b0 = *(const uint4*)(bp + k0 + 64); b1 = *(const uint4*)(bp + k0 + 72);
      }
#pragma unroll
      for (int ks = 0; ks < 2; ++ks) {
        bf16x8 af[2], bff[2];
#pragma unroll
        for (int f = 0; f < 2; ++f) {
          af[f]  = *(const bf16x8*)&As[wr * 32 + f * 16 + fr][ks * 32 + kb];
          bff[f] = *(const bf16x8*)&Bs[wc * 32 + f * 16 + fr][ks * 32 + kb];
        }
#pragma unroll
        for (int i = 0; i < 2; ++i)
#pragma unroll
          for (int j = 0; j < 2; ++j)
            acc[i][j] = MFMA16(af[i], bff[j], acc[i][j]);
      }
    }
    const int lrow = (lane >> 4) << 2, lcol = lane & 15;
#pragma unroll
    for (int i = 0; i < 2; ++i)
#pragma unroll
      for (int j = 0; j < 2; ++j)
#pragma unroll
        for (int r = 0; r < 4; ++r) {
          const int m = m0 + wr * 32 + i * 16 + lrow + r;
          const int n = n0 + wc * 32 + j * 16 + lcol;
          C[(size_t)m * 1024 + n] = acc[i][j][r];
        }
    return;
  }

  // ---- relv MFMA ----
  const int bi = blockIdx.x - 256, b = bi >> 9, i = bi & 511;
  bf16* p_lds = (bf16*)&smem_raw[0];       // [9][536] (row 8 = garbage pad)
  bf16* rvT   = (bf16*)&smem_raw[9648];    // [128][64], block-rotated
  const int w = t >> 6, lane = t & 63;
  const int fr = lane & 15, fg = lane >> 4;

  // stage p (all 512 j, rows h=0..7)
  {
    const int h = t >> 5, j0 = (t & 31) << 4;
    const bf16* src = P + (((size_t)(b * 8 + h) * 512) + i) * 512 + j0;
    const uint4 v0 = *(const uint4*)src;
    const uint4 v1 = *(const uint4*)(src + 8);
    *(uint4*)&p_lds[h * 536 + j0]     = v0;
    *(uint4*)&p_lds[h * 536 + j0 + 8] = v1;
  }

  const int arow = (fr < 8) ? fr : 8;
  const int ct0 = w * 2, ct1 = w * 2 + 1;
  f32x4 acc0 = (f32x4){0.f, 0.f, 0.f, 0.f};
  f32x4 acc1 = (f32x4){0.f, 0.f, 0.f, 0.f};

  for (int ch = 0; ch < 8; ++ch) {
    const int j0 = ch * 64;
    __syncthreads();          // prior MFMA reads (and p-stage) complete
    // stage rvT chunk: 64 j x 128 d, transposed with block rotation
    {
      const int jj = t >> 5, d0 = (t & 31) << 2;
#pragma unroll
      for (int ps = 0; ps < 8; ++ps) {
        const int j = jj + ps * 8;   // local 0..63
        const float4 rr = *(const float4*)&rvg[((size_t)bi * 512 + j0 + j) * 128 + d0];
        const float vr[4] = {rr.x, rr.y, rr.z, rr.w};
#pragma unroll
        for (int r = 0; r < 4; ++r) {
          const int d = d0 + r;
          const int blk = ((j >> 3) + (d >> 2)) & 7;
          rvT[d * 64 + blk * 8 + (j & 7)] = (bf16)vr[r];
        }
      }
    }
    __syncthreads();
    // MFMA: 2 k-subtiles x 2 d-col-tiles
#pragma unroll
    for (int kl = 0; kl < 2; ++kl) {
      const int jsub = kl * 32 + fg * 8;
      const bf16x8 af = *(const bf16x8*)&p_lds[arow * 536 + j0 + jsub];
      {
        const int d = ct0 * 16 + fr;
        const int blk = ((jsub >> 3) + (d >> 2)) & 7;
        const bf16x8 bf_ = *(const bf16x8*)&rvT[d * 64 + blk * 8];
        acc0 = MFMA16(af, bf_, acc0);
      }
      {
        const int d = ct1 * 16 + fr;
        const int blk = ((jsub >> 3) + (d >> 2)) & 7;
        const bf16x8 bf_ = *(const bf16x8*)&rvT[d * 64 + blk * 8];
        acc1 = MFMA16(af, bf_, acc1);
      }
    }
  }

  // store: lane holds D[h = fg*4+r][d = ct*16+fr]; only h<8 valid
  if (fg < 2) {
    float* xrow = xa + ((size_t)(b * 512 + i)) * 1024;
#pragma unroll
    for (int r = 0; r < 4; ++r) {
      const int h = fg * 4 + r;
      xrow[h * 128 + ct0 * 16 + fr] = acc0[r];
      xrow[h * 128 + ct1 * 16 + fr] = acc1[r];
    }
  }
}

// =====================================================================
// Output projection: Cf[m*1024+n] = (xa + xb2) @ W^T + bias
// =====================================================================
__global__ __launch_bounds__(256)
void proj_out(const float* __restrict__ A, const float* __restrict__ A2,
              const float* __restrict__ W,
              const float* __restrict__ bias, float* __restrict__ Cf)
{
  __shared__ bf16 As[64][72];
  __shared__ bf16 Bs[64][72];
  const int t = threadIdx.x;
  const int m0 = (blockIdx.x >> 4) << 6;
  const int n0 = (blockIdx.x & 15) << 6;
  const int wave = t >> 6, lane = t & 63;
  const int wr = wave >> 1, wc = wave & 1;
  const int srow = t >> 2, skc = (t & 3) << 4;
  const float* Ap  = A  + (size_t)(m0 + srow) * 1024 + skc;
  const float* A2p = A2 + (size_t)(m0 + srow) * 1024 + skc;
  const float* Wp  = W  + (size_t)(n0 + srow) * 1024 + skc;
  const int fr = lane & 15, kb = (lane >> 4) << 3;
  f32x4 acc[2][2];
#pragma unroll
  for (int i = 0; i < 2; ++i)
#pragma unroll
    for (int j = 0; j < 2; ++j) acc[i][j] = (f32x4){0.f, 0.f, 0.f, 0.f};

  float4 a4[4], w4[4], a4n[4], w4n[4];
#pragma unroll
  for (int u = 0; u < 4; ++u) {
    const float4 x1 = *(const float4*)(Ap + u * 4);
    const float4 x2 = *(const float4*)(A2p + u * 4);
    a4[u] = make_float4(x1.x + x2.x, x1.y + x2.y, x1.z + x2.z, x1.w + x2.w);
    w4[u] = *(const float4*)(Wp + u * 4);
  }
  for (int k0 = 0; k0 < 1024; k0 += 64) {
    __syncthreads();
    *(bf16x8*)&As[srow][skc]     = cvt8(a4[0], a4[1]);
    *(bf16x8*)&As[srow][skc + 8] = cvt8(a4[2], a4[3]);
    *(bf16x8*)&Bs[srow][skc]     = cvt8(w4[0], w4[1]);
    *(bf16x8*)&Bs[srow][skc + 8] = cvt8(w4[2], w4[3]);
    __syncthreads();
    if (k0 + 64 < 1024) {
#pragma unroll
      for (int u = 0; u < 4; ++u) {
        const float4 x1 = *(const float4*)(Ap + k0 + 64 + u * 4);
        const float4 x2 = *(const float4*)(A2p + k0 + 64 + u * 4);
        a4n[u] = make_float4(x1.x + x2.x, x1.y + x2.y, x1.z + x2.z, x1.w + x2.w);
        w4n[u] = *(const float4*)(Wp + k0 + 64 + u * 4);
      }
    }
#pragma unroll
    for (int ks = 0; ks < 2; ++ks) {
      bf16x8 af[2], bff[2];
#pragma unroll
      for (int f = 0; f < 2; ++f) {
        af[f]  = *(const bf16x8*)&As[wr * 32 + f * 16 + fr][ks * 32 + kb];
        bff[f] = *(const bf16x8*)&Bs[wc * 32 + f * 16 + fr][ks * 32 + kb];
      }
#pragma unroll
      for (int i = 0; i < 2; ++i)
#pragma unroll
        for (int j = 0; j < 2; ++j)
          acc[i][j] = MFMA16(af[i], bff[j], acc[i][j]);
    }
#pragma unroll
    for (int u = 0; u < 4; ++u) { a4[u] = a4n[u]; w4[u] = w4n[u]; }
  }
  const int lrow = (lane >> 4) << 2, lcol = lane & 15;
#pragma unroll
  for (int i = 0; i < 2; ++i) {
#pragma unroll
    for (int j = 0; j < 2; ++j) {
      const int n = n0 + wc * 32 + j * 16 + lcol;
      const float bvl = bias[n];
#pragma unroll
      for (int r = 0; r < 4; ++r) {
        const int m = m0 + wr * 32 + i * 16 + lrow + r;
        Cf[(size_t)m * 1024 + n] = acc[i][j][r] + bvl;
      }
    }
  }
}

// =====================================================================
extern "C" void kernel_launch(void* const* d_in, const int* in_sizes, int n_in,
                              void* d_out, int out_size, void* d_ws, size_t ws_size,
                              hipStream_t stream)
{
  const float* query = (const float*)d_in[0];
  const float* key   = (const float*)d_in[1];
  const float* value = (const float*)d_in[2];
  const float* rk    = (const float*)d_in[3];
  const float* rv    = (const float*)d_in[4];
  const int*   mask  = (const int*)d_in[5];
  const int*   sep   = (const int*)d_in[6];
  const float* hreg  = (const float*)d_in[7];
  const float* Wq    = (const float*)d_in[8];
  const float* bq    = (const float*)d_in[9];
  const float* Wk    = (const float*)d_in[10];
  const float* bk    = (const float*)d_in[11];
  const float* Wv    = (const float*)d_in[12];
  const float* bv    = (const float*)d_in[13];
  const float* Wo    = (const float*)d_in[14];
  const float* bo    = (const float*)d_in[15];
  const float* hw    = (const float*)d_in[16];
  float* out = (float*)d_out;

  float* ws  = (float*)d_ws;
  float* qb  = ws;                           // 1,048,576 f32
  float* sc  = qb + 1048576;                 // 4,194,304 f32
  float* xa  = sc + 4194304;                 // 1,048,576 f32
  float* xb2 = xa + 1048576;                 // 1,048,576 f32
  float* gb  = xb2 + 1048576;                //     8,192 f32
  bf16* qb16 = (bf16*)(gb + 8192);           // 1,048,576 bf16
  bf16* kb16 = qb16 + 1048576;               // 1,048,576 bf16
  bf16* vt16 = kb16 + 1048576;               // 1,048,576 bf16
  bf16* pb16 = vt16 + 1048576;               // 4,194,304 bf16

  proj3_mfma<<<dim3(256, 3), 256, 0, stream>>>(query, key, value,
                                               Wq, Wk, Wv, bq, bk, bv,
                                               qb, qb16, kb16, vt16);
  qs_fat<<<dim3(1025), 256, 0, stream>>>(qb16, kb16, sc,
                                         qb, hw, sep, hreg, gb, out + 1048576);
  relk_sm<<<dim3(1024), 256, 0, stream>>>(qb, rk, sc, mask, gb, pb16);
  relv_fat<<<dim3(1280), 256, 0, stream>>>(pb16, vt16, rv, xb2, xa);
  proj_out<<<dim3(256), 256, 0, stream>>>(xa, xb2, Wo, bo, out);
}

// Round 10
// 176.507 us; speedup vs baseline: 2.5206x; 1.0687x over previous
//
#include <hip/hip_runtime.h>

static constexpr float SCALE = 0.08838834764831845f; // 1/sqrt(128)

typedef __bf16 bf16;
typedef __bf16 bf16x8 __attribute__((ext_vector_type(8)));
typedef float  f32x4  __attribute__((ext_vector_type(4)));

#define MFMA16(a, b, c) __builtin_amdgcn_mfma_f32_16x16x32_bf16((a), (b), (c), 0, 0, 0)

__device__ inline bf16x8 cvt8(const float4& x, const float4& y) {
  bf16x8 r;
  r[0] = (bf16)x.x; r[1] = (bf16)x.y; r[2] = (bf16)x.z; r[3] = (bf16)x.w;
  r[4] = (bf16)y.x; r[5] = (bf16)y.y; r[6] = (bf16)y.z; r[7] = (bf16)y.w;
  return r;
}

// =====================================================================
// cvt_bf16: convert 7 fp32 tensors (1M elements each) to bf16.
// blockIdx.y selects tensor; 512 blocks x 256 thr x 8 elem.
// =====================================================================
__global__ __launch_bounds__(256)
void cvt_bf16(const float* __restrict__ s0, const float* __restrict__ s1,
              const float* __restrict__ s2, const float* __restrict__ s3,
              const float* __restrict__ s4, const float* __restrict__ s5,
              const float* __restrict__ s6,
              bf16* __restrict__ d0, bf16* __restrict__ d1,
              bf16* __restrict__ d2, bf16* __restrict__ d3,
              bf16* __restrict__ d4, bf16* __restrict__ d5,
              bf16* __restrict__ d6)
{
  const int sel = blockIdx.y;
  const float* src = sel == 0 ? s0 : sel == 1 ? s1 : sel == 2 ? s2 :
                     sel == 3 ? s3 : sel == 4 ? s4 : sel == 5 ? s5 : s6;
  bf16* dst = sel == 0 ? d0 : sel == 1 ? d1 : sel == 2 ? d2 :
              sel == 3 ? d3 : sel == 4 ? d4 : sel == 5 ? d5 : d6;
  const size_t idx = ((size_t)blockIdx.x * 256 + threadIdx.x) * 8;
  const float4 a = *(const float4*)(src + idx);
  const float4 b = *(const float4*)(src + idx + 4);
  *(bf16x8*)(dst + idx) = cvt8(a, b);
}

// =====================================================================
// Batched projection GEMM, pure bf16 (q,k,v in one launch).
// sel==0 (q): fp32 qf + bf16 q16 in [b,h,i,dk]
// sel==1 (k): bf16 k16 in [b,h,i,dk]
// sel==2 (v): bf16 vt16 TRANSPOSED [b,h,dk,i]
// =====================================================================
__global__ __launch_bounds__(256)
void proj3_mfma2(const bf16* __restrict__ Aq, const bf16* __restrict__ Ak,
                 const bf16* __restrict__ Av,
                 const bf16* __restrict__ Wq, const bf16* __restrict__ Wk,
                 const bf16* __restrict__ Wv,
                 const float* __restrict__ bq, const float* __restrict__ bk,
                 const float* __restrict__ bv,
                 float* __restrict__ qf, bf16* __restrict__ q16,
                 bf16* __restrict__ k16, bf16* __restrict__ vt16)
{
  const int sel = blockIdx.y;
  const bf16* A     = sel == 0 ? Aq : (sel == 1 ? Ak : Av);
  const bf16* W     = sel == 0 ? Wq : (sel == 1 ? Wk : Wv);
  const float* bias = sel == 0 ? bq : (sel == 1 ? bk : bv);

  __shared__ bf16 As[64][72];
  __shared__ bf16 Bs[64][72];
  const int t = threadIdx.x;
  const int m0 = (blockIdx.x >> 4) << 6;
  const int n0 = (blockIdx.x & 15) << 6;
  const int wave = t >> 6, lane = t & 63;
  const int wr = wave >> 1, wc = wave & 1;
  const int srow = t >> 2, skc = (t & 3) << 4;
  const bf16* Ap = A + (size_t)(m0 + srow) * 1024 + skc;
  const bf16* Wp = W + (size_t)(n0 + srow) * 1024 + skc;
  const int fr = lane & 15, kb = (lane >> 4) << 3;
  f32x4 acc[2][2];
#pragma unroll
  for (int i = 0; i < 2; ++i)
#pragma unroll
    for (int j = 0; j < 2; ++j) acc[i][j] = (f32x4){0.f, 0.f, 0.f, 0.f};

  uint4 a0 = *(const uint4*)Ap, a1 = *(const uint4*)(Ap + 8);
  uint4 b0 = *(const uint4*)Wp, b1 = *(const uint4*)(Wp + 8);
  uint4 a0n, a1n, b0n, b1n;
  for (int k0 = 0; k0 < 1024; k0 += 64) {
    __syncthreads();
    *(uint4*)&As[srow][skc]     = a0; *(uint4*)&As[srow][skc + 8] = a1;
    *(uint4*)&Bs[srow][skc]     = b0; *(uint4*)&Bs[srow][skc + 8] = b1;
    __syncthreads();
    if (k0 + 64 < 1024) {
      a0n = *(const uint4*)(Ap + k0 + 64); a1n = *(const uint4*)(Ap + k0 + 72);
      b0n = *(const uint4*)(Wp + k0 + 64); b1n = *(const uint4*)(Wp + k0 + 72);
    }
#pragma unroll
    for (int ks = 0; ks < 2; ++ks) {
      bf16x8 af[2], bff[2];
#pragma unroll
      for (int f = 0; f < 2; ++f) {
        af[f]  = *(const bf16x8*)&As[wr * 32 + f * 16 + fr][ks * 32 + kb];
        bff[f] = *(const bf16x8*)&Bs[wc * 32 + f * 16 + fr][ks * 32 + kb];
      }
#pragma unroll
      for (int i = 0; i < 2; ++i)
#pragma unroll
        for (int j = 0; j < 2; ++j)
          acc[i][j] = MFMA16(af[i], bff[j], acc[i][j]);
    }
    a0 = a0n; a1 = a1n; b0 = b0n; b1 = b1n;
  }
  const int lrow = (lane >> 4) << 2, lcol = lane & 15;
#pragma unroll
  for (int i = 0; i < 2; ++i) {
#pragma unroll
    for (int j = 0; j < 2; ++j) {
      const int n = n0 + wc * 32 + j * 16 + lcol;
      const float bvl = bias[n];
#pragma unroll
      for (int r = 0; r < 4; ++r) {
        const int m = m0 + wr * 32 + i * 16 + lrow + r;
        const float val = acc[i][j][r] + bvl;
        const int b = m >> 9, ii = m & 511, h = n >> 7, dk = n & 127;
        if (sel == 2) {
          vt16[(((size_t)(b * 8 + h) * 128) + dk) * 512 + ii] = (bf16)val;
        } else {
          const size_t idx = (((size_t)(b * 8 + h) * 512) + ii) * 128 + dk;
          if (sel == 0) { qf[idx] = val; q16[idx] = (bf16)val; }
          else          { k16[idx] = (bf16)val; }
        }
      }
    }
  }
}

// =====================================================================
// qs_fat: blocks 0..1023 = QK^T MFMA (sc = q16 @ k16^T, overwrite);
//         block 1024     = sep/gating/loss.
// =====================================================================
__global__ __launch_bounds__(256)
void qs_fat(const bf16* __restrict__ Q, const bf16* __restrict__ Kb,
            float* __restrict__ scores,
            const float* __restrict__ qf, const float* __restrict__ hw,
            const int* __restrict__ sep_id, const float* __restrict__ hreg,
            float* __restrict__ g, float* __restrict__ loss_out)
{
  __shared__ bf16 As[64][72];
  __shared__ bf16 Bs[64][72];
  __shared__ float pool[16][4];
  __shared__ float spred[16][4];
  __shared__ float lbuf[16];
  __shared__ int sids[4];
  const int t = threadIdx.x;

  if (blockIdx.x >= 1024) {
    if (t < 4) sids[t] = sep_id[t];
    __syncthreads();
    {
      const int dot = t >> 2, sub = t & 3;
      const int bh = dot >> 2, n = dot & 3;
      const int b = bh >> 3, h = bh & 7;
      const int row = sids[n];
      const float* qp = qf + (((size_t)(b * 8 + h) * 512) + row) * 128 + sub * 32;
      const float* wp = hw + h * 128 + sub * 32;
      float s = 0.f;
#pragma unroll
      for (int dd = 0; dd < 32; ++dd) s = fmaf(qp[dd], wp[dd], s);
      s += __shfl_xor(s, 1);
      s += __shfl_xor(s, 2);
      if (sub == 0) pool[bh][n] = s;
    }
    __syncthreads();
    if (t < 16) {
      float pv[4];
#pragma unroll
      for (int n = 0; n < 4; ++n) pv[n] = pool[t][n];
      float mx = fmaxf(fmaxf(pv[0], pv[1]), fmaxf(pv[2], pv[3]));
      float sum = 0.f;
#pragma unroll
      for (int n = 0; n < 4; ++n) { pv[n] = expf(pv[n] - mx); sum += pv[n]; }
      const float inv = 1.f / sum;
      float maxp = 0.f, l2 = 0.f;
#pragma unroll
      for (int n = 0; n < 4; ++n) {
        const float pr = pv[n] * inv;
        spred[t][n] = pr;
        maxp = fmaxf(maxp, pr);
        const float tg = hreg[n];
        l2 += tg * (logf(tg) - logf(pr));
      }
      lbuf[t] = (1.f - maxp) / 16.f + l2 / 64.f;
    }
    __syncthreads();
    if (t == 0) {
      float L = 0.f;
#pragma unroll
      for (int r = 0; r < 16; ++r) L += lbuf[r];
      loss_out[0] = L;
    }
    for (int idx = t; idx < 16 * 512; idx += 256) {
      const int bh = idx >> 9, pp = idx & 511;
      float gg = 0.f;
#pragma unroll
      for (int n = 0; n < 4; ++n)
        gg += spred[bh][n] * (pp >= sids[n] ? 1.f : 0.f);
      g[idx] = gg;
    }
    return;
  }

  const int bh = blockIdx.x >> 6, tile = blockIdx.x & 63;
  const bf16* A = Q  + (size_t)bh * (512 * 128);
  const bf16* B = Kb + (size_t)bh * (512 * 128);
  float* C = scores + (size_t)bh * (512 * 512);
  const int m0 = (tile >> 3) << 6, n0 = (tile & 7) << 6;
  const int wave = t >> 6, lane = t & 63;
  const int wr = wave >> 1, wc = wave & 1;
  const int srow = t >> 2, skc = (t & 3) << 4;
  const int fr = lane & 15, kb = (lane >> 4) << 3;
  f32x4 acc[2][2];
#pragma unroll
  for (int i = 0; i < 2; ++i)
#pragma unroll
    for (int j = 0; j < 2; ++j) acc[i][j] = (f32x4){0.f, 0.f, 0.f, 0.f};

  const bf16* ap = A + (size_t)(m0 + srow) * 128 + skc;
  const bf16* bp = B + (size_t)(n0 + srow) * 128 + skc;
  uint4 a0 = *(const uint4*)ap, a1 = *(const uint4*)(ap + 8);
  uint4 b0 = *(const uint4*)bp, b1 = *(const uint4*)(bp + 8);
  for (int k0 = 0; k0 < 128; k0 += 64) {
    __syncthreads();
    *(uint4*)&As[srow][skc]     = a0; *(uint4*)&As[srow][skc + 8] = a1;
    *(uint4*)&Bs[srow][skc]     = b0; *(uint4*)&Bs[srow][skc + 8] = b1;
    __syncthreads();
    if (k0 == 0) {
      a0 = *(const uint4*)(ap + 64); a1 = *(const uint4*)(ap + 72);
      b0 = *(const uint4*)(bp + 64); b1 = *(const uint4*)(bp + 72);
    }
#pragma unroll
    for (int ks = 0; ks < 2; ++ks) {
      bf16x8 af[2], bff[2];
#pragma unroll
      for (int f = 0; f < 2; ++f) {
        af[f]  = *(const bf16x8*)&As[wr * 32 + f * 16 + fr][ks * 32 + kb];
        bff[f] = *(const bf16x8*)&Bs[wc * 32 + f * 16 + fr][ks * 32 + kb];
      }
#pragma unroll
      for (int i = 0; i < 2; ++i)
#pragma unroll
        for (int j = 0; j < 2; ++j)
          acc[i][j] = MFMA16(af[i], bff[j], acc[i][j]);
    }
  }
  const int lrow = (lane >> 4) << 2, lcol = lane & 15;
#pragma unroll
  for (int i = 0; i < 2; ++i)
#pragma unroll
    for (int j = 0; j < 2; ++j)
#pragma unroll
      for (int r = 0; r < 4; ++r) {
        const int m = m0 + wr * 32 + i * 16 + lrow + r;
        const int n = n0 + wc * 32 + j * 16 + lcol;
        C[(size_t)m * 512 + n] = acc[i][j][r];
      }
}

// =====================================================================
// relk_sm: per (b,i) block.
// Phase 1 (MFMA): rel[j,h] = rk[b,i] (512x128) @ q16(16x128)^T
// Phase 2: softmax((sc+rel)*SCALE, mask, factor) -> pb16.
// =====================================================================
__global__ __launch_bounds__(256)
void relk_sm(const bf16* __restrict__ q16, const float* __restrict__ rk,
             const float* __restrict__ sc, const int* __restrict__ mask,
             const float* __restrict__ g, bf16* __restrict__ pb)
{
  const int bi = blockIdx.x, b = bi >> 9, i = bi & 511;
  __shared__ float rel_[8 * 516];
  const int t = threadIdx.x;
  const int w = t >> 6, lane = t & 63;
  const int fr = lane & 15, fg = lane >> 4;

  // B-frags: q16[h=fr][k = kt*32 + fg*8 + e], zero for fr >= 8
  bf16x8 bq[4];
#pragma unroll
  for (int kt = 0; kt < 4; ++kt) {
    if (fr < 8) {
      bq[kt] = *(const bf16x8*)&q16[(((size_t)(b * 8 + fr) * 512) + i) * 128
                                    + kt * 32 + fg * 8];
    } else {
#pragma unroll
      for (int e = 0; e < 8; ++e) bq[kt][e] = (bf16)0.f;
    }
  }

  const float* rkb = rk + (size_t)bi * 512 * 128;
  for (int c = 0; c < 8; ++c) {
    const int jb = c * 64 + w * 16;
    const float* rp = rkb + (size_t)(jb + fr) * 128 + fg * 8;
    float4 a[8];
#pragma unroll
    for (int kt = 0; kt < 4; ++kt) {
      a[kt * 2]     = *(const float4*)(rp + kt * 32);
      a[kt * 2 + 1] = *(const float4*)(rp + kt * 32 + 4);
    }
    f32x4 acc = (f32x4){0.f, 0.f, 0.f, 0.f};
#pragma unroll
    for (int kt = 0; kt < 4; ++kt)
      acc = MFMA16(cvt8(a[kt * 2], a[kt * 2 + 1]), bq[kt], acc);
    if (fr < 8) {
#pragma unroll
      for (int r = 0; r < 4; ++r)
        rel_[fr * 516 + jb + fg * 4 + r] = acc[r];
    }
  }
  __syncthreads();

  // phase 2: softmax per head row
  const int h = t >> 5, ln = t & 31;
  const float* scrow = sc + (((size_t)(b * 8 + h) * 512) + i) * 512;
  const int* mrow = mask + ((size_t)(b * 512 + i)) * 512;
  const float* grow = g + (b * 8 + h) * 512;
  const float gi = grow[i];
  float s[16];
  float mx = -3.402823466e+38f;
#pragma unroll
  for (int k = 0; k < 16; ++k) {
    const int j = ln + (k << 5);
    float sv = (scrow[j] + rel_[h * 516 + j]) * SCALE;
    if (mrow[j] == 0) sv = -1.0e9f;
    const float fac = (j >= i) ? gi : grow[j];
    sv *= fac;
    s[k] = sv;
    mx = fmaxf(mx, sv);
  }
#pragma unroll
  for (int off = 16; off > 0; off >>= 1) mx = fmaxf(mx, __shfl_xor(mx, off));
  float sum = 0.f;
#pragma unroll
  for (int k = 0; k < 16; ++k) { const float e = __expf(s[k] - mx); s[k] = e; sum += e; }
#pragma unroll
  for (int off = 16; off > 0; off >>= 1) sum += __shfl_xor(sum, off);
  const float inv = 1.f / sum;
  bf16* prow = pb + (((size_t)(b * 8 + h) * 512) + i) * 512;
#pragma unroll
  for (int k = 0; k < 16; ++k) {
    const int j = ln + (k << 5);
    prow[j] = (bf16)(s[k] * inv);
  }
}

// =====================================================================
// relv_fat:
//  blocks 0..255    = PV MFMA (xb2 = p16 @ vt16, overwrite)
//  blocks 256..1279 = relv MFMA per (b,i) with rv transposed into LDS.
// =====================================================================
__global__ __launch_bounds__(256)
void relv_fat(const bf16* __restrict__ P, const bf16* __restrict__ VT,
              const float* __restrict__ rvg,
              float* __restrict__ xb2, float* __restrict__ xa)
{
  __shared__ __align__(16) char smem_raw[26032];
  const int t = threadIdx.x;

  if (blockIdx.x < 256) {
    bf16 (*As)[72] = (bf16(*)[72])&smem_raw[0];
    bf16 (*Bs)[72] = (bf16(*)[72])&smem_raw[9216];
    const int bh = blockIdx.x >> 4, tile = blockIdx.x & 15;
    const int b = bh >> 3, h = bh & 7;
    const bf16* A = P  + (size_t)bh * (512 * 512);
    const bf16* B = VT + (size_t)bh * (128 * 512);
    float* C = xb2 + (size_t)b * (512 * 1024) + h * 128;
    const int m0 = (tile >> 1) << 6, n0 = (tile & 1) << 6;
    const int wave = t >> 6, lane = t & 63;
    const int wr = wave >> 1, wc = wave & 1;
    const int srow = t >> 2, skc = (t & 3) << 4;
    const int fr = lane & 15, kb = (lane >> 4) << 3;
    f32x4 acc[2][2];
#pragma unroll
    for (int i = 0; i < 2; ++i)
#pragma unroll
      for (int j = 0; j < 2; ++j) acc[i][j] = (f32x4){0.f, 0.f, 0.f, 0.f};

    const bf16* ap = A + (size_t)(m0 + srow) * 512 + skc;
    const bf16* bp = B + (size_t)(n0 + srow) * 512 + skc;
    uint4 a0 = *(const uint4*)ap, a1 = *(const uint4*)(ap + 8);
    uint4 b0 = *(const uint4*)bp, b1 = *(const uint4*)(bp + 8);
    for (int k0 = 0; k0 < 512; k0 += 64) {
      __syncthreads();
      *(uint4*)&As[srow][skc]     = a0; *(uint4*)&As[srow][skc + 8] = a1;
      *(uint4*)&Bs[srow][skc]     = b0; *(uint4*)&Bs[srow][skc + 8] = b1;
      __syncthreads();
      if (k0 + 64 < 512) {
        a0 = *(const uint4*)(ap + k0 + 64); a1 = *(const uint4*)(ap + k0 + 72);
        b0 = *(const uint4*)(bp + k0 + 64); b1 = *(const uint4*)(bp + k0 + 72);
      }
#pragma unroll
      for (int ks = 0; ks < 2; ++ks) {
        bf16x8 af[2], bff[2];
#pragma unroll
        for (int f = 0; f < 2; ++f) {
          af[f]  = *(const bf16x8*)&As[wr * 32 + f * 16 + fr][ks * 32 + kb];
          bff[f] = *(const bf16x8*)&Bs[wc * 32 + f * 16 + fr][ks * 32 + kb];
        }
#pragma unroll
        for (int i = 0; i < 2; ++i)
#pragma unroll
          for (int j = 0; j < 2; ++j)
            acc[i][j] = MFMA16(af[i], bff[j], acc[i][j]);
      }
    }
    const int lrow = (lane >> 4) << 2, lcol = lane & 15;
#pragma unroll
    for (int i = 0; i < 2; ++i)
#pragma unroll
      for (int j = 0; j < 2; ++j)
#pragma unroll
        for (int r = 0; r < 4; ++r) {
          const int m = m0 + wr * 32 + i * 16 + lrow + r;
          const int n = n0 + wc * 32 + j * 16 + lcol;
          C[(size_t)m * 1024 + n] = acc[i][j][r];
        }
    return;
  }

  // ---- relv MFMA ----
  const int bi = blockIdx.x - 256, b = bi >> 9, i = bi & 511;
  bf16* p_lds = (bf16*)&smem_raw[0];       // [9][536]
  bf16* rvT   = (bf16*)&smem_raw[9648];    // [128][64], block-rotated
  const int w = t >> 6, lane = t & 63;
  const int fr = lane & 15, fg = lane >> 4;

  {
    const int h = t >> 5, j0 = (t & 31) << 4;
    const bf16* src = P + (((size_t)(b * 8 + h) * 512) + i) * 512 + j0;
    const uint4 v0 = *(const uint4*)src;
    const uint4 v1 = *(const uint4*)(src + 8);
    *(uint4*)&p_lds[h * 536 + j0]     = v0;
    *(uint4*)&p_lds[h * 536 + j0 + 8] = v1;
  }

  const int arow = (fr < 8) ? fr : 8;
  const int ct0 = w * 2, ct1 = w * 2 + 1;
  f32x4 acc0 = (f32x4){0.f, 0.f, 0.f, 0.f};
  f32x4 acc1 = (f32x4){0.f, 0.f, 0.f, 0.f};

  for (int ch = 0; ch < 8; ++ch) {
    const int j0 = ch * 64;
    __syncthreads();
    {
      const int jj = t >> 5, d0 = (t & 31) << 2;
#pragma unroll
      for (int ps = 0; ps < 8; ++ps) {
        const int j = jj + ps * 8;
        const float4 rr = *(const float4*)&rvg[((size_t)bi * 512 + j0 + j) * 128 + d0];
        const float vr[4] = {rr.x, rr.y, rr.z, rr.w};
#pragma unroll
        for (int r = 0; r < 4; ++r) {
          const int d = d0 + r;
          const int blk = ((j >> 3) + (d >> 2)) & 7;
          rvT[d * 64 + blk * 8 + (j & 7)] = (bf16)vr[r];
        }
      }
    }
    __syncthreads();
#pragma unroll
    for (int kl = 0; kl < 2; ++kl) {
      const int jsub = kl * 32 + fg * 8;
      const bf16x8 af = *(const bf16x8*)&p_lds[arow * 536 + j0 + jsub];
      {
        const int d = ct0 * 16 + fr;
        const int blk = ((jsub >> 3) + (d >> 2)) & 7;
        const bf16x8 bf_ = *(const bf16x8*)&rvT[d * 64 + blk * 8];
        acc0 = MFMA16(af, bf_, acc0);
      }
      {
        const int d = ct1 * 16 + fr;
        const int blk = ((jsub >> 3) + (d >> 2)) & 7;
        const bf16x8 bf_ = *(const bf16x8*)&rvT[d * 64 + blk * 8];
        acc1 = MFMA16(af, bf_, acc1);
      }
    }
  }

  if (fg < 2) {
    float* xrow = xa + ((size_t)(b * 512 + i)) * 1024;
#pragma unroll
    for (int r = 0; r < 4; ++r) {
      const int h = fg * 4 + r;
      xrow[h * 128 + ct0 * 16 + fr] = acc0[r];
      xrow[h * 128 + ct1 * 16 + fr] = acc1[r];
    }
  }
}

// =====================================================================
// Output projection: Cf[m*1024+n] = (xa + xb2) @ Wo16^T + bias
// =====================================================================
__global__ __launch_bounds__(256)
void proj_out2(const float* __restrict__ A, const float* __restrict__ A2,
               const bf16* __restrict__ W16,
               const float* __restrict__ bias, float* __restrict__ Cf)
{
  __shared__ bf16 As[64][72];
  __shared__ bf16 Bs[64][72];
  const int t = threadIdx.x;
  const int m0 = (blockIdx.x >> 4) << 6;
  const int n0 = (blockIdx.x & 15) << 6;
  const int wave = t >> 6, lane = t & 63;
  const int wr = wave >> 1, wc = wave & 1;
  const int srow = t >> 2, skc = (t & 3) << 4;
  const float* Ap  = A   + (size_t)(m0 + srow) * 1024 + skc;
  const float* A2p = A2  + (size_t)(m0 + srow) * 1024 + skc;
  const bf16*  Wp  = W16 + (size_t)(n0 + srow) * 1024 + skc;
  const int fr = lane & 15, kb = (lane >> 4) << 3;
  f32x4 acc[2][2];
#pragma unroll
  for (int i = 0; i < 2; ++i)
#pragma unroll
    for (int j = 0; j < 2; ++j) acc[i][j] = (f32x4){0.f, 0.f, 0.f, 0.f};

  float4 a4[4], a4n[4];
  uint4 b0 = *(const uint4*)Wp, b1 = *(const uint4*)(Wp + 8);
  uint4 b0n, b1n;
#pragma unroll
  for (int u = 0; u < 4; ++u) {
    const float4 x1 = *(const float4*)(Ap + u * 4);
    const float4 x2 = *(const float4*)(A2p + u * 4);
    a4[u] = make_float4(x1.x + x2.x, x1.y + x2.y, x1.z + x2.z, x1.w + x2.w);
  }
  for (int k0 = 0; k0 < 1024; k0 += 64) {
    __syncthreads();
    *(bf16x8*)&As[srow][skc]     = cvt8(a4[0], a4[1]);
    *(bf16x8*)&As[srow][skc + 8] = cvt8(a4[2], a4[3]);
    *(uint4*)&Bs[srow][skc]      = b0;
    *(uint4*)&Bs[srow][skc + 8]  = b1;
    __syncthreads();
    if (k0 + 64 < 1024) {
#pragma unroll
      for (int u = 0; u < 4; ++u) {
        const float4 x1 = *(const float4*)(Ap + k0 + 64 + u * 4);
        const float4 x2 = *(const float4*)(A2p + k0 + 64 + u * 4);
        a4n[u] = make_float4(x1.x + x2.x, x1.y + x2.y, x1.z + x2.z, x1.w + x2.w);
      }
      b0n = *(const uint4*)(Wp + k0 + 64);
      b1n = *(const uint4*)(Wp + k0 + 72);
    }
#pragma unroll
    for (int ks = 0; ks < 2; ++ks) {
      bf16x8 af[2], bff[2];
#pragma unroll
      for (int f = 0; f < 2; ++f) {
        af[f]  = *(const bf16x8*)&As[wr * 32 + f * 16 + fr][ks * 32 + kb];
        bff[f] = *(const bf16x8*)&Bs[wc * 32 + f * 16 + fr][ks * 32 + kb];
      }
#pragma unroll
      for (int i = 0; i < 2; ++i)
#pragma unroll
        for (int j = 0; j < 2; ++j)
          acc[i][j] = MFMA16(af[i], bff[j], acc[i][j]);
    }
#pragma unroll
    for (int u = 0; u < 4; ++u) a4[u] = a4n[u];
    b0 = b0n; b1 = b1n;
  }
  const int lrow = (lane >> 4) << 2, lcol = lane & 15;
#pragma unroll
  for (int i = 0; i < 2; ++i) {
#pragma unroll
    for (int j = 0; j < 2; ++j) {
      const int n = n0 + wc * 32 + j * 16 + lcol;
      const float bvl = bias[n];
#pragma unroll
      for (int r = 0; r < 4; ++r) {
        const int m = m0 + wr * 32 + i * 16 + lrow + r;
        Cf[(size_t)m * 1024 + n] = acc[i][j][r] + bvl;
      }
    }
  }
}

// =====================================================================
extern "C" void kernel_launch(void* const* d_in, const int* in_sizes, int n_in,
                              void* d_out, int out_size, void* d_ws, size_t ws_size,
                              hipStream_t stream)
{
  const float* query = (const float*)d_in[0];
  const float* key   = (const float*)d_in[1];
  const float* value = (const float*)d_in[2];
  const float* rk    = (const float*)d_in[3];
  const float* rv    = (const float*)d_in[4];
  const int*   mask  = (const int*)d_in[5];
  const int*   sep   = (const int*)d_in[6];
  const float* hreg  = (const float*)d_in[7];
  const float* Wq    = (const float*)d_in[8];
  const float* bq    = (const float*)d_in[9];
  const float* Wk    = (const float*)d_in[10];
  const float* bk    = (const float*)d_in[11];
  const float* Wv    = (const float*)d_in[12];
  const float* bv    = (const float*)d_in[13];
  const float* Wo    = (const float*)d_in[14];
  const float* bo    = (const float*)d_in[15];
  const float* hw    = (const float*)d_in[16];
  float* out = (float*)d_out;

  float* ws  = (float*)d_ws;
  float* qb  = ws;                           // 1,048,576 f32
  float* sc  = qb + 1048576;                 // 4,194,304 f32
  float* xa  = sc + 4194304;                 // 1,048,576 f32
  float* xb2 = xa + 1048576;                 // 1,048,576 f32
  float* gb  = xb2 + 1048576;                //     8,192 f32
  bf16* qb16 = (bf16*)(gb + 8192);           // 1,048,576 bf16
  bf16* kb16 = qb16 + 1048576;               // 1,048,576 bf16
  bf16* vt16 = kb16 + 1048576;               // 1,048,576 bf16
  bf16* pb16 = vt16 + 1048576;               // 4,194,304 bf16
  // conversion buffers: first 4 alias pb16 (dead until relk_sm writes it)
  bf16* qA16 = pb16;                         // 1,048,576 bf16
  bf16* kA16 = qA16 + 1048576;
  bf16* vA16 = kA16 + 1048576;
  bf16* Wq16 = vA16 + 1048576;
  bf16* Wk16 = pb16 + 4194304;               // +1,048,576 (new)
  bf16* Wv16 = Wk16 + 1048576;
  bf16* Wo16 = Wv16 + 1048576;

  cvt_bf16<<<dim3(512, 7), 256, 0, stream>>>(query, key, value, Wq, Wk, Wv, Wo,
                                             qA16, kA16, vA16, Wq16, Wk16, Wv16,
                                             Wo16);
  proj3_mfma2<<<dim3(256, 3), 256, 0, stream>>>(qA16, kA16, vA16,
                                                Wq16, Wk16, Wv16, bq, bk, bv,
                                                qb, qb16, kb16, vt16);
  qs_fat<<<dim3(1025), 256, 0, stream>>>(qb16, kb16, sc,
                                         qb, hw, sep, hreg, gb, out + 1048576);
  relk_sm<<<dim3(1024), 256, 0, stream>>>(qb16, rk, sc, mask, gb, pb16);
  relv_fat<<<dim3(1280), 256, 0, stream>>>(pb16, vt16, rv, xb2, xa);
  proj_out2<<<dim3(256), 256, 0, stream>>>(xa, xb2, Wo16, bo, out);
}

// Round 11
// 174.815 us; speedup vs baseline: 2.5450x; 1.0097x over previous
//
#include <hip/hip_runtime.h>

static constexpr float SCALE = 0.08838834764831845f; // 1/sqrt(128)

typedef __bf16 bf16;
typedef __bf16 bf16x8 __attribute__((ext_vector_type(8)));
typedef float  f32x4  __attribute__((ext_vector_type(4)));

#define MFMA16(a, b, c) __builtin_amdgcn_mfma_f32_16x16x32_bf16((a), (b), (c), 0, 0, 0)

__device__ inline bf16x8 cvt8(const float4& x, const float4& y) {
  bf16x8 r;
  r[0] = (bf16)x.x; r[1] = (bf16)x.y; r[2] = (bf16)x.z; r[3] = (bf16)x.w;
  r[4] = (bf16)y.x; r[5] = (bf16)y.y; r[6] = (bf16)y.z; r[7] = (bf16)y.w;
  return r;
}

// =====================================================================
// cvt_bf16: convert 7 fp32 tensors (1M elements each) to bf16.
// =====================================================================
__global__ __launch_bounds__(256)
void cvt_bf16(const float* __restrict__ s0, const float* __restrict__ s1,
              const float* __restrict__ s2, const float* __restrict__ s3,
              const float* __restrict__ s4, const float* __restrict__ s5,
              const float* __restrict__ s6,
              bf16* __restrict__ d0, bf16* __restrict__ d1,
              bf16* __restrict__ d2, bf16* __restrict__ d3,
              bf16* __restrict__ d4, bf16* __restrict__ d5,
              bf16* __restrict__ d6)
{
  const int sel = blockIdx.y;
  const float* src = sel == 0 ? s0 : sel == 1 ? s1 : sel == 2 ? s2 :
                     sel == 3 ? s3 : sel == 4 ? s4 : sel == 5 ? s5 : s6;
  bf16* dst = sel == 0 ? d0 : sel == 1 ? d1 : sel == 2 ? d2 :
              sel == 3 ? d3 : sel == 4 ? d4 : sel == 5 ? d5 : d6;
  const size_t idx = ((size_t)blockIdx.x * 256 + threadIdx.x) * 8;
  const float4 a = *(const float4*)(src + idx);
  const float4 b = *(const float4*)(src + idx + 4);
  *(bf16x8*)(dst + idx) = cvt8(a, b);
}

// =====================================================================
// Batched projection GEMM, pure bf16, LDS DOUBLE-BUFFER (1 barrier/iter).
// sel==0 (q): fp32 qf + bf16 q16 in [b,h,i,dk]
// sel==1 (k): bf16 k16 in [b,h,i,dk]
// sel==2 (v): bf16 vt16 TRANSPOSED [b,h,dk,i]
// =====================================================================
__global__ __launch_bounds__(256)
void proj3_mfma2(const bf16* __restrict__ Aq, const bf16* __restrict__ Ak,
                 const bf16* __restrict__ Av,
                 const bf16* __restrict__ Wq, const bf16* __restrict__ Wk,
                 const bf16* __restrict__ Wv,
                 const float* __restrict__ bq, const float* __restrict__ bk,
                 const float* __restrict__ bv,
                 float* __restrict__ qf, bf16* __restrict__ q16,
                 bf16* __restrict__ k16, bf16* __restrict__ vt16)
{
  const int sel = blockIdx.y;
  const bf16* A     = sel == 0 ? Aq : (sel == 1 ? Ak : Av);
  const bf16* W     = sel == 0 ? Wq : (sel == 1 ? Wk : Wv);
  const float* bias = sel == 0 ? bq : (sel == 1 ? bk : bv);

  __shared__ bf16 As[2][64][72];
  __shared__ bf16 Bs[2][64][72];
  const int t = threadIdx.x;
  const int m0 = (blockIdx.x >> 4) << 6;
  const int n0 = (blockIdx.x & 15) << 6;
  const int wave = t >> 6, lane = t & 63;
  const int wr = wave >> 1, wc = wave & 1;
  const int srow = t >> 2, skc = (t & 3) << 4;
  const bf16* Ap = A + (size_t)(m0 + srow) * 1024 + skc;
  const bf16* Wp = W + (size_t)(n0 + srow) * 1024 + skc;
  const int fr = lane & 15, kb = (lane >> 4) << 3;
  f32x4 acc[2][2];
#pragma unroll
  for (int i = 0; i < 2; ++i)
#pragma unroll
    for (int j = 0; j < 2; ++j) acc[i][j] = (f32x4){0.f, 0.f, 0.f, 0.f};

  uint4 a0 = *(const uint4*)Ap, a1 = *(const uint4*)(Ap + 8);
  uint4 b0 = *(const uint4*)Wp, b1 = *(const uint4*)(Wp + 8);
  uint4 a0n, a1n, b0n, b1n;
  for (int k0 = 0; k0 < 1024; k0 += 64) {
    const int buf = (k0 >> 6) & 1;
    *(uint4*)&As[buf][srow][skc]     = a0; *(uint4*)&As[buf][srow][skc + 8] = a1;
    *(uint4*)&Bs[buf][srow][skc]     = b0; *(uint4*)&Bs[buf][srow][skc + 8] = b1;
    if (k0 + 64 < 1024) {
      a0n = *(const uint4*)(Ap + k0 + 64); a1n = *(const uint4*)(Ap + k0 + 72);
      b0n = *(const uint4*)(Wp + k0 + 64); b1n = *(const uint4*)(Wp + k0 + 72);
    }
    __syncthreads();
#pragma unroll
    for (int ks = 0; ks < 2; ++ks) {
      bf16x8 af[2], bff[2];
#pragma unroll
      for (int f = 0; f < 2; ++f) {
        af[f]  = *(const bf16x8*)&As[buf][wr * 32 + f * 16 + fr][ks * 32 + kb];
        bff[f] = *(const bf16x8*)&Bs[buf][wc * 32 + f * 16 + fr][ks * 32 + kb];
      }
#pragma unroll
      for (int i = 0; i < 2; ++i)
#pragma unroll
        for (int j = 0; j < 2; ++j)
          acc[i][j] = MFMA16(af[i], bff[j], acc[i][j]);
    }
    a0 = a0n; a1 = a1n; b0 = b0n; b1 = b1n;
  }
  const int lrow = (lane >> 4) << 2, lcol = lane & 15;
#pragma unroll
  for (int i = 0; i < 2; ++i) {
#pragma unroll
    for (int j = 0; j < 2; ++j) {
      const int n = n0 + wc * 32 + j * 16 + lcol;
      const float bvl = bias[n];
#pragma unroll
      for (int r = 0; r < 4; ++r) {
        const int m = m0 + wr * 32 + i * 16 + lrow + r;
        const float val = acc[i][j][r] + bvl;
        const int b = m >> 9, ii = m & 511, h = n >> 7, dk = n & 127;
        if (sel == 2) {
          vt16[(((size_t)(b * 8 + h) * 128) + dk) * 512 + ii] = (bf16)val;
        } else {
          const size_t idx = (((size_t)(b * 8 + h) * 512) + ii) * 128 + dk;
          if (sel == 0) { qf[idx] = val; q16[idx] = (bf16)val; }
          else          { k16[idx] = (bf16)val; }
        }
      }
    }
  }
}

// =====================================================================
// qs_fat: blocks 0..1023 = QK^T MFMA (sc = q16 @ k16^T, overwrite);
//         block 1024     = sep/gating/loss.
// =====================================================================
__global__ __launch_bounds__(256)
void qs_fat(const bf16* __restrict__ Q, const bf16* __restrict__ Kb,
            float* __restrict__ scores,
            const float* __restrict__ qf, const float* __restrict__ hw,
            const int* __restrict__ sep_id, const float* __restrict__ hreg,
            float* __restrict__ g, float* __restrict__ loss_out)
{
  __shared__ bf16 As[64][72];
  __shared__ bf16 Bs[64][72];
  __shared__ float pool[16][4];
  __shared__ float spred[16][4];
  __shared__ float lbuf[16];
  __shared__ int sids[4];
  const int t = threadIdx.x;

  if (blockIdx.x >= 1024) {
    if (t < 4) sids[t] = sep_id[t];
    __syncthreads();
    {
      const int dot = t >> 2, sub = t & 3;
      const int bh = dot >> 2, n = dot & 3;
      const int b = bh >> 3, h = bh & 7;
      const int row = sids[n];
      const float* qp = qf + (((size_t)(b * 8 + h) * 512) + row) * 128 + sub * 32;
      const float* wp = hw + h * 128 + sub * 32;
      float s = 0.f;
#pragma unroll
      for (int dd = 0; dd < 32; ++dd) s = fmaf(qp[dd], wp[dd], s);
      s += __shfl_xor(s, 1);
      s += __shfl_xor(s, 2);
      if (sub == 0) pool[bh][n] = s;
    }
    __syncthreads();
    if (t < 16) {
      float pv[4];
#pragma unroll
      for (int n = 0; n < 4; ++n) pv[n] = pool[t][n];
      float mx = fmaxf(fmaxf(pv[0], pv[1]), fmaxf(pv[2], pv[3]));
      float sum = 0.f;
#pragma unroll
      for (int n = 0; n < 4; ++n) { pv[n] = expf(pv[n] - mx); sum += pv[n]; }
      const float inv = 1.f / sum;
      float maxp = 0.f, l2 = 0.f;
#pragma unroll
      for (int n = 0; n < 4; ++n) {
        const float pr = pv[n] * inv;
        spred[t][n] = pr;
        maxp = fmaxf(maxp, pr);
        const float tg = hreg[n];
        l2 += tg * (logf(tg) - logf(pr));
      }
      lbuf[t] = (1.f - maxp) / 16.f + l2 / 64.f;
    }
    __syncthreads();
    if (t == 0) {
      float L = 0.f;
#pragma unroll
      for (int r = 0; r < 16; ++r) L += lbuf[r];
      loss_out[0] = L;
    }
    for (int idx = t; idx < 16 * 512; idx += 256) {
      const int bh = idx >> 9, pp = idx & 511;
      float gg = 0.f;
#pragma unroll
      for (int n = 0; n < 4; ++n)
        gg += spred[bh][n] * (pp >= sids[n] ? 1.f : 0.f);
      g[idx] = gg;
    }
    return;
  }

  const int bh = blockIdx.x >> 6, tile = blockIdx.x & 63;
  const bf16* A = Q  + (size_t)bh * (512 * 128);
  const bf16* B = Kb + (size_t)bh * (512 * 128);
  float* C = scores + (size_t)bh * (512 * 512);
  const int m0 = (tile >> 3) << 6, n0 = (tile & 7) << 6;
  const int wave = t >> 6, lane = t & 63;
  const int wr = wave >> 1, wc = wave & 1;
  const int srow = t >> 2, skc = (t & 3) << 4;
  const int fr = lane & 15, kb = (lane >> 4) << 3;
  f32x4 acc[2][2];
#pragma unroll
  for (int i = 0; i < 2; ++i)
#pragma unroll
    for (int j = 0; j < 2; ++j) acc[i][j] = (f32x4){0.f, 0.f, 0.f, 0.f};

  const bf16* ap = A + (size_t)(m0 + srow) * 128 + skc;
  const bf16* bp = B + (size_t)(n0 + srow) * 128 + skc;
  uint4 a0 = *(const uint4*)ap, a1 = *(const uint4*)(ap + 8);
  uint4 b0 = *(const uint4*)bp, b1 = *(const uint4*)(bp + 8);
  for (int k0 = 0; k0 < 128; k0 += 64) {
    __syncthreads();
    *(uint4*)&As[srow][skc]     = a0; *(uint4*)&As[srow][skc + 8] = a1;
    *(uint4*)&Bs[srow][skc]     = b0; *(uint4*)&Bs[srow][skc + 8] = b1;
    __syncthreads();
    if (k0 == 0) {
      a0 = *(const uint4*)(ap + 64); a1 = *(const uint4*)(ap + 72);
      b0 = *(const uint4*)(bp + 64); b1 = *(const uint4*)(bp + 72);
    }
#pragma unroll
    for (int ks = 0; ks < 2; ++ks) {
      bf16x8 af[2], bff[2];
#pragma unroll
      for (int f = 0; f < 2; ++f) {
        af[f]  = *(const bf16x8*)&As[wr * 32 + f * 16 + fr][ks * 32 + kb];
        bff[f] = *(const bf16x8*)&Bs[wc * 32 + f * 16 + fr][ks * 32 + kb];
      }
#pragma unroll
      for (int i = 0; i < 2; ++i)
#pragma unroll
        for (int j = 0; j < 2; ++j)
          acc[i][j] = MFMA16(af[i], bff[j], acc[i][j]);
    }
  }
  const int lrow = (lane >> 4) << 2, lcol = lane & 15;
#pragma unroll
  for (int i = 0; i < 2; ++i)
#pragma unroll
    for (int j = 0; j < 2; ++j)
#pragma unroll
      for (int r = 0; r < 4; ++r) {
        const int m = m0 + wr * 32 + i * 16 + lrow + r;
        const int n = n0 + wc * 32 + j * 16 + lcol;
        C[(size_t)m * 512 + n] = acc[i][j][r];
      }
}

// =====================================================================
// relk_sm: per (b,i) block.
// Phase 1 (MFMA): rel[j,h] = rk[b,i] (512x128) @ q16(16x128)^T
// Phase 2: softmax((sc+rel)*SCALE, mask, factor) -> pb16.
// =====================================================================
__global__ __launch_bounds__(256)
void relk_sm(const bf16* __restrict__ q16, const float* __restrict__ rk,
             const float* __restrict__ sc, const int* __restrict__ mask,
             const float* __restrict__ g, bf16* __restrict__ pb)
{
  const int bi = blockIdx.x, b = bi >> 9, i = bi & 511;
  __shared__ float rel_[8 * 516];
  const int t = threadIdx.x;
  const int w = t >> 6, lane = t & 63;
  const int fr = lane & 15, fg = lane >> 4;

  bf16x8 bq[4];
#pragma unroll
  for (int kt = 0; kt < 4; ++kt) {
    if (fr < 8) {
      bq[kt] = *(const bf16x8*)&q16[(((size_t)(b * 8 + fr) * 512) + i) * 128
                                    + kt * 32 + fg * 8];
    } else {
#pragma unroll
      for (int e = 0; e < 8; ++e) bq[kt][e] = (bf16)0.f;
    }
  }

  const float* rkb = rk + (size_t)bi * 512 * 128;
  for (int c = 0; c < 8; ++c) {
    const int jb = c * 64 + w * 16;
    const float* rp = rkb + (size_t)(jb + fr) * 128 + fg * 8;
    float4 a[8];
#pragma unroll
    for (int kt = 0; kt < 4; ++kt) {
      a[kt * 2]     = *(const float4*)(rp + kt * 32);
      a[kt * 2 + 1] = *(const float4*)(rp + kt * 32 + 4);
    }
    f32x4 acc = (f32x4){0.f, 0.f, 0.f, 0.f};
#pragma unroll
    for (int kt = 0; kt < 4; ++kt)
      acc = MFMA16(cvt8(a[kt * 2], a[kt * 2 + 1]), bq[kt], acc);
    if (fr < 8) {
#pragma unroll
      for (int r = 0; r < 4; ++r)
        rel_[fr * 516 + jb + fg * 4 + r] = acc[r];
    }
  }
  __syncthreads();

  const int h = t >> 5, ln = t & 31;
  const float* scrow = sc + (((size_t)(b * 8 + h) * 512) + i) * 512;
  const int* mrow = mask + ((size_t)(b * 512 + i)) * 512;
  const float* grow = g + (b * 8 + h) * 512;
  const float gi = grow[i];
  float s[16];
  float mx = -3.402823466e+38f;
#pragma unroll
  for (int k = 0; k < 16; ++k) {
    const int j = ln + (k << 5);
    float sv = (scrow[j] + rel_[h * 516 + j]) * SCALE;
    if (mrow[j] == 0) sv = -1.0e9f;
    const float fac = (j >= i) ? gi : grow[j];
    sv *= fac;
    s[k] = sv;
    mx = fmaxf(mx, sv);
  }
#pragma unroll
  for (int off = 16; off > 0; off >>= 1) mx = fmaxf(mx, __shfl_xor(mx, off));
  float sum = 0.f;
#pragma unroll
  for (int k = 0; k < 16; ++k) { const float e = __expf(s[k] - mx); s[k] = e; sum += e; }
#pragma unroll
  for (int off = 16; off > 0; off >>= 1) sum += __shfl_xor(sum, off);
  const float inv = 1.f / sum;
  bf16* prow = pb + (((size_t)(b * 8 + h) * 512) + i) * 512;
#pragma unroll
  for (int k = 0; k < 16; ++k) {
    const int j = ln + (k << 5);
    prow[j] = (bf16)(s[k] * inv);
  }
}

// =====================================================================
// relv_fat:
//  blocks 0..255    = PV MFMA (xb2 = p16 @ vt16, overwrite)
//  blocks 256..1279 = relv MFMA per (b,i), DIRECT global A-frags:
//     D[m=d, n=h] = sum_j rv[j,d] * p[h,j]; no LDS transpose, 1 barrier.
// =====================================================================
__global__ __launch_bounds__(256)
void relv_fat(const bf16* __restrict__ P, const bf16* __restrict__ VT,
              const float* __restrict__ rvg,
              float* __restrict__ xb2, float* __restrict__ xa)
{
  __shared__ __align__(16) char smem_raw[18432];
  const int t = threadIdx.x;

  if (blockIdx.x < 256) {
    bf16 (*As)[72] = (bf16(*)[72])&smem_raw[0];
    bf16 (*Bs)[72] = (bf16(*)[72])&smem_raw[9216];
    const int bh = blockIdx.x >> 4, tile = blockIdx.x & 15;
    const int b = bh >> 3, h = bh & 7;
    const bf16* A = P  + (size_t)bh * (512 * 512);
    const bf16* B = VT + (size_t)bh * (128 * 512);
    float* C = xb2 + (size_t)b * (512 * 1024) + h * 128;
    const int m0 = (tile >> 1) << 6, n0 = (tile & 1) << 6;
    const int wave = t >> 6, lane = t & 63;
    const int wr = wave >> 1, wc = wave & 1;
    const int srow = t >> 2, skc = (t & 3) << 4;
    const int fr = lane & 15, kb = (lane >> 4) << 3;
    f32x4 acc[2][2];
#pragma unroll
    for (int i = 0; i < 2; ++i)
#pragma unroll
      for (int j = 0; j < 2; ++j) acc[i][j] = (f32x4){0.f, 0.f, 0.f, 0.f};

    const bf16* ap = A + (size_t)(m0 + srow) * 512 + skc;
    const bf16* bp = B + (size_t)(n0 + srow) * 512 + skc;
    uint4 a0 = *(const uint4*)ap, a1 = *(const uint4*)(ap + 8);
    uint4 b0 = *(const uint4*)bp, b1 = *(const uint4*)(bp + 8);
    for (int k0 = 0; k0 < 512; k0 += 64) {
      __syncthreads();
      *(uint4*)&As[srow][skc]     = a0; *(uint4*)&As[srow][skc + 8] = a1;
      *(uint4*)&Bs[srow][skc]     = b0; *(uint4*)&Bs[srow][skc + 8] = b1;
      __syncthreads();
      if (k0 + 64 < 512) {
        a0 = *(const uint4*)(ap + k0 + 64); a1 = *(const uint4*)(ap + k0 + 72);
        b0 = *(const uint4*)(bp + k0 + 64); b1 = *(const uint4*)(bp + k0 + 72);
      }
#pragma unroll
      for (int ks = 0; ks < 2; ++ks) {
        bf16x8 af[2], bff[2];
#pragma unroll
        for (int f = 0; f < 2; ++f) {
          af[f]  = *(const bf16x8*)&As[wr * 32 + f * 16 + fr][ks * 32 + kb];
          bff[f] = *(const bf16x8*)&Bs[wc * 32 + f * 16 + fr][ks * 32 + kb];
        }
#pragma unroll
        for (int i = 0; i < 2; ++i)
#pragma unroll
          for (int j = 0; j < 2; ++j)
            acc[i][j] = MFMA16(af[i], bff[j], acc[i][j]);
      }
    }
    const int lrow = (lane >> 4) << 2, lcol = lane & 15;
#pragma unroll
    for (int i = 0; i < 2; ++i)
#pragma unroll
      for (int j = 0; j < 2; ++j)
#pragma unroll
        for (int r = 0; r < 4; ++r) {
          const int m = m0 + wr * 32 + i * 16 + lrow + r;
          const int n = n0 + wc * 32 + j * 16 + lcol;
          C[(size_t)m * 1024 + n] = acc[i][j][r];
        }
    return;
  }

  // ---- relv MFMA, direct A-frags ----
  const int bi = blockIdx.x - 256, b = bi >> 9, i = bi & 511;
  bf16* p_lds = (bf16*)&smem_raw[0];       // [8][536]
  const int w = t >> 6, lane = t & 63;
  const int fr = lane & 15, fg = lane >> 4;

  // stage p rows h=0..7
  {
    const int h = t >> 5, j0 = (t & 31) << 4;
    const bf16* src = P + (((size_t)(b * 8 + h) * 512) + i) * 512 + j0;
    const uint4 v0 = *(const uint4*)src;
    const uint4 v1 = *(const uint4*)(src + 8);
    *(uint4*)&p_lds[h * 536 + j0]     = v0;
    *(uint4*)&p_lds[h * 536 + j0 + 8] = v1;
  }
  __syncthreads();

  const int ct0 = w * 2, ct1 = w * 2 + 1;   // d-tiles (16 d each)
  f32x4 acc0 = (f32x4){0.f, 0.f, 0.f, 0.f};
  f32x4 acc1 = (f32x4){0.f, 0.f, 0.f, 0.f};
  const float* rvb = rvg + (size_t)bi * 512 * 128;

  for (int js = 0; js < 16; ++js) {
    const int jb = js * 32 + fg * 8;
    const bf16x8 bp = *(const bf16x8*)&p_lds[(fr & 7) * 536 + jb];
    float a0v[8], a1v[8];
#pragma unroll
    for (int e = 0; e < 8; ++e) {
      const float* col = rvb + (size_t)(jb + e) * 128 + fr;
      a0v[e] = col[ct0 * 16];
      a1v[e] = col[ct1 * 16];
    }
    bf16x8 af0, af1;
#pragma unroll
    for (int e = 0; e < 8; ++e) { af0[e] = (bf16)a0v[e]; af1[e] = (bf16)a1v[e]; }
    acc0 = MFMA16(af0, bp, acc0);
    acc1 = MFMA16(af1, bp, acc1);
  }

  // D[m = ct*16 + fg*4 + r (d), n = fr (h)]; only h<8 stored
  if (fr < 8) {
    float* xrow = xa + ((size_t)(b * 512 + i)) * 1024 + fr * 128;
#pragma unroll
    for (int r = 0; r < 4; ++r) {
      xrow[ct0 * 16 + fg * 4 + r] = acc0[r];
      xrow[ct1 * 16 + fg * 4 + r] = acc1[r];
    }
  }
}

// =====================================================================
// Output projection, LDS double-buffer: Cf = (xa + xb2) @ Wo16^T + bias
// =====================================================================
__global__ __launch_bounds__(256)
void proj_out2(const float* __restrict__ A, const float* __restrict__ A2,
               const bf16* __restrict__ W16,
               const float* __restrict__ bias, float* __restrict__ Cf)
{
  __shared__ bf16 As[2][64][72];
  __shared__ bf16 Bs[2][64][72];
  const int t = threadIdx.x;
  const int m0 = (blockIdx.x >> 4) << 6;
  const int n0 = (blockIdx.x & 15) << 6;
  const int wave = t >> 6, lane = t & 63;
  const int wr = wave >> 1, wc = wave & 1;
  const int srow = t >> 2, skc = (t & 3) << 4;
  const float* Ap  = A   + (size_t)(m0 + srow) * 1024 + skc;
  const float* A2p = A2  + (size_t)(m0 + srow) * 1024 + skc;
  const bf16*  Wp  = W16 + (size_t)(n0 + srow) * 1024 + skc;
  const int fr = lane & 15, kb = (lane >> 4) << 3;
  f32x4 acc[2][2];
#pragma unroll
  for (int i = 0; i < 2; ++i)
#pragma unroll
    for (int j = 0; j < 2; ++j) acc[i][j] = (f32x4){0.f, 0.f, 0.f, 0.f};

  float4 a4[4], a4n[4];
  uint4 b0 = *(const uint4*)Wp, b1 = *(const uint4*)(Wp + 8);
  uint4 b0n, b1n;
#pragma unroll
  for (int u = 0; u < 4; ++u) {
    const float4 x1 = *(const float4*)(Ap + u * 4);
    const float4 x2 = *(const float4*)(A2p + u * 4);
    a4[u] = make_float4(x1.x + x2.x, x1.y + x2.y, x1.z + x2.z, x1.w + x2.w);
  }
  for (int k0 = 0; k0 < 1024; k0 += 64) {
    const int buf = (k0 >> 6) & 1;
    *(bf16x8*)&As[buf][srow][skc]     = cvt8(a4[0], a4[1]);
    *(bf16x8*)&As[buf][srow][skc + 8] = cvt8(a4[2], a4[3]);
    *(uint4*)&Bs[buf][srow][skc]      = b0;
    *(uint4*)&Bs[buf][srow][skc + 8]  = b1;
    if (k0 + 64 < 1024) {
#pragma unroll
      for (int u = 0; u < 4; ++u) {
        const float4 x1 = *(const float4*)(Ap + k0 + 64 + u * 4);
        const float4 x2 = *(const float4*)(A2p + k0 + 64 + u * 4);
        a4n[u] = make_float4(x1.x + x2.x, x1.y + x2.y, x1.z + x2.z, x1.w + x2.w);
      }
      b0n = *(const uint4*)(Wp + k0 + 64);
      b1n = *(const uint4*)(Wp + k0 + 72);
    }
    __syncthreads();
#pragma unroll
    for (int ks = 0; ks < 2; ++ks) {
      bf16x8 af[2], bff[2];
#pragma unroll
      for (int f = 0; f < 2; ++f) {
        af[f]  = *(const bf16x8*)&As[buf][wr * 32 + f * 16 + fr][ks * 32 + kb];
        bff[f] = *(const bf16x8*)&Bs[buf][wc * 32 + f * 16 + fr][ks * 32 + kb];
      }
#pragma unroll
      for (int i = 0; i < 2; ++i)
#pragma unroll
        for (int j = 0; j < 2; ++j)
          acc[i][j] = MFMA16(af[i], bff[j], acc[i][j]);
    }
#pragma unroll
    for (int u = 0; u < 4; ++u) a4[u] = a4n[u];
    b0 = b0n; b1 = b1n;
  }
  const int lrow = (lane >> 4) << 2, lcol = lane & 15;
#pragma unroll
  for (int i = 0; i < 2; ++i) {
#pragma unroll
    for (int j = 0; j < 2; ++j) {
      const int n = n0 + wc * 32 + j * 16 + lcol;
      const float bvl = bias[n];
#pragma unroll
      for (int r = 0; r < 4; ++r) {
        const int m = m0 + wr * 32 + i * 16 + lrow + r;
        Cf[(size_t)m * 1024 + n] = acc[i][j][r] + bvl;
      }
    }
  }
}

// =====================================================================
extern "C" void kernel_launch(void* const* d_in, const int* in_sizes, int n_in,
                              void* d_out, int out_size, void* d_ws, size_t ws_size,
                              hipStream_t stream)
{
  const float* query = (const float*)d_in[0];
  const float* key   = (const float*)d_in[1];
  const float* value = (const float*)d_in[2];
  const float* rk    = (const float*)d_in[3];
  const float* rv    = (const float*)d_in[4];
  const int*   mask  = (const int*)d_in[5];
  const int*   sep   = (const int*)d_in[6];
  const float* hreg  = (const float*)d_in[7];
  const float* Wq    = (const float*)d_in[8];
  const float* bq    = (const float*)d_in[9];
  const float* Wk    = (const float*)d_in[10];
  const float* bk    = (const float*)d_in[11];
  const float* Wv    = (const float*)d_in[12];
  const float* bv    = (const float*)d_in[13];
  const float* Wo    = (const float*)d_in[14];
  const float* bo    = (const float*)d_in[15];
  const float* hw    = (const float*)d_in[16];
  float* out = (float*)d_out;

  float* ws  = (float*)d_ws;
  float* qb  = ws;                           // 1,048,576 f32
  float* sc  = qb + 1048576;                 // 4,194,304 f32
  float* xa  = sc + 4194304;                 // 1,048,576 f32
  float* xb2 = xa + 1048576;                 // 1,048,576 f32
  float* gb  = xb2 + 1048576;                //     8,192 f32
  bf16* qb16 = (bf16*)(gb + 8192);           // 1,048,576 bf16
  bf16* kb16 = qb16 + 1048576;               // 1,048,576 bf16
  bf16* vt16 = kb16 + 1048576;               // 1,048,576 bf16
  bf16* pb16 = vt16 + 1048576;               // 4,194,304 bf16
  // conversion buffers: first 4 alias pb16 (dead until relk_sm writes it)
  bf16* qA16 = pb16;
  bf16* kA16 = qA16 + 1048576;
  bf16* vA16 = kA16 + 1048576;
  bf16* Wq16 = vA16 + 1048576;
  bf16* Wk16 = pb16 + 4194304;
  bf16* Wv16 = Wk16 + 1048576;
  bf16* Wo16 = Wv16 + 1048576;

  cvt_bf16<<<dim3(512, 7), 256, 0, stream>>>(query, key, value, Wq, Wk, Wv, Wo,
                                             qA16, kA16, vA16, Wq16, Wk16, Wv16,
                                             Wo16);
  proj3_mfma2<<<dim3(256, 3), 256, 0, stream>>>(qA16, kA16, vA16,
                                                Wq16, Wk16, Wv16, bq, bk, bv,
                                                qb, qb16, kb16, vt16);
  qs_fat<<<dim3(1025), 256, 0, stream>>>(qb16, kb16, sc,
                                         qb, hw, sep, hreg, gb, out + 1048576);
  relk_sm<<<dim3(1024), 256, 0, stream>>>(qb16, rk, sc, mask, gb, pb16);
  relv_fat<<<dim3(1280), 256, 0, stream>>>(pb16, vt16, rv, xb2, xa);
  proj_out2<<<dim3(256), 256, 0, stream>>>(xa, xb2, Wo16, bo, out);
}

// Round 12
// 173.397 us; speedup vs baseline: 2.5658x; 1.0082x over previous
//
#include <hip/hip_runtime.h>

static constexpr float SCALE = 0.08838834764831845f; // 1/sqrt(128)

typedef __bf16 bf16;
typedef __bf16 bf16x8 __attribute__((ext_vector_type(8)));
typedef float  f32x4  __attribute__((ext_vector_type(4)));

#define MFMA16(a, b, c) __builtin_amdgcn_mfma_f32_16x16x32_bf16((a), (b), (c), 0, 0, 0)

__device__ inline bf16x8 cvt8(const float4& x, const float4& y) {
  bf16x8 r;
  r[0] = (bf16)x.x; r[1] = (bf16)x.y; r[2] = (bf16)x.z; r[3] = (bf16)x.w;
  r[4] = (bf16)y.x; r[5] = (bf16)y.y; r[6] = (bf16)y.z; r[7] = (bf16)y.w;
  return r;
}

// =====================================================================
// cvt_bf16: convert 7 fp32 tensors (1M elements each) to bf16.
// =====================================================================
__global__ __launch_bounds__(256)
void cvt_bf16(const float* __restrict__ s0, const float* __restrict__ s1,
              const float* __restrict__ s2, const float* __restrict__ s3,
              const float* __restrict__ s4, const float* __restrict__ s5,
              const float* __restrict__ s6,
              bf16* __restrict__ d0, bf16* __restrict__ d1,
              bf16* __restrict__ d2, bf16* __restrict__ d3,
              bf16* __restrict__ d4, bf16* __restrict__ d5,
              bf16* __restrict__ d6)
{
  const int sel = blockIdx.y;
  const float* src = sel == 0 ? s0 : sel == 1 ? s1 : sel == 2 ? s2 :
                     sel == 3 ? s3 : sel == 4 ? s4 : sel == 5 ? s5 : s6;
  bf16* dst = sel == 0 ? d0 : sel == 1 ? d1 : sel == 2 ? d2 :
              sel == 3 ? d3 : sel == 4 ? d4 : sel == 5 ? d5 : d6;
  const size_t idx = ((size_t)blockIdx.x * 256 + threadIdx.x) * 8;
  const float4 a = *(const float4*)(src + idx);
  const float4 b = *(const float4*)(src + idx + 4);
  *(bf16x8*)(dst + idx) = cvt8(a, b);
}

// =====================================================================
// Batched projection GEMM, pure bf16, LDS double-buffer.
// sel==0 (q): fp32 qf + bf16 q16 in [b,h,i,dk]
// sel==1 (k): bf16 k16 in [b,h,i,dk]
// sel==2 (v): bf16 vt16 TRANSPOSED [b,h,dk,i] via LDS-transposed epilogue
// =====================================================================
__global__ __launch_bounds__(256)
void proj3_mfma2(const bf16* __restrict__ Aq, const bf16* __restrict__ Ak,
                 const bf16* __restrict__ Av,
                 const bf16* __restrict__ Wq, const bf16* __restrict__ Wk,
                 const bf16* __restrict__ Wv,
                 const float* __restrict__ bq, const float* __restrict__ bk,
                 const float* __restrict__ bv,
                 float* __restrict__ qf, bf16* __restrict__ q16,
                 bf16* __restrict__ k16, bf16* __restrict__ vt16)
{
  const int sel = blockIdx.y;
  const bf16* A     = sel == 0 ? Aq : (sel == 1 ? Ak : Av);
  const bf16* W     = sel == 0 ? Wq : (sel == 1 ? Wk : Wv);
  const float* bias = sel == 0 ? bq : (sel == 1 ? bk : bv);

  __shared__ bf16 As[2][64][72];
  __shared__ bf16 Bs[2][64][72];
  const int t = threadIdx.x;
  const int m0 = (blockIdx.x >> 4) << 6;
  const int n0 = (blockIdx.x & 15) << 6;
  const int wave = t >> 6, lane = t & 63;
  const int wr = wave >> 1, wc = wave & 1;
  const int srow = t >> 2, skc = (t & 3) << 4;
  const bf16* Ap = A + (size_t)(m0 + srow) * 1024 + skc;
  const bf16* Wp = W + (size_t)(n0 + srow) * 1024 + skc;
  const int fr = lane & 15, kb = (lane >> 4) << 3;
  f32x4 acc[2][2];
#pragma unroll
  for (int i = 0; i < 2; ++i)
#pragma unroll
    for (int j = 0; j < 2; ++j) acc[i][j] = (f32x4){0.f, 0.f, 0.f, 0.f};

  uint4 a0 = *(const uint4*)Ap, a1 = *(const uint4*)(Ap + 8);
  uint4 b0 = *(const uint4*)Wp, b1 = *(const uint4*)(Wp + 8);
  uint4 a0n, a1n, b0n, b1n;
  for (int k0 = 0; k0 < 1024; k0 += 64) {
    const int buf = (k0 >> 6) & 1;
    *(uint4*)&As[buf][srow][skc]     = a0; *(uint4*)&As[buf][srow][skc + 8] = a1;
    *(uint4*)&Bs[buf][srow][skc]     = b0; *(uint4*)&Bs[buf][srow][skc + 8] = b1;
    if (k0 + 64 < 1024) {
      a0n = *(const uint4*)(Ap + k0 + 64); a1n = *(const uint4*)(Ap + k0 + 72);
      b0n = *(const uint4*)(Wp + k0 + 64); b1n = *(const uint4*)(Wp + k0 + 72);
    }
    __syncthreads();
#pragma unroll
    for (int ks = 0; ks < 2; ++ks) {
      bf16x8 af[2], bff[2];
#pragma unroll
      for (int f = 0; f < 2; ++f) {
        af[f]  = *(const bf16x8*)&As[buf][wr * 32 + f * 16 + fr][ks * 32 + kb];
        bff[f] = *(const bf16x8*)&Bs[buf][wc * 32 + f * 16 + fr][ks * 32 + kb];
      }
#pragma unroll
      for (int i = 0; i < 2; ++i)
#pragma unroll
        for (int j = 0; j < 2; ++j)
          acc[i][j] = MFMA16(af[i], bff[j], acc[i][j]);
    }
    a0 = a0n; a1 = a1n; b0 = b0n; b1 = b1n;
  }
  const int lrow = (lane >> 4) << 2, lcol = lane & 15;

  if (sel == 2) {
    // LDS-transposed epilogue: T[n_local][m_local] bf16, stride 72
    bf16* T = &As[0][0][0];
    __syncthreads();                  // all MFMA LDS reads done
#pragma unroll
    for (int i = 0; i < 2; ++i) {
#pragma unroll
      for (int j = 0; j < 2; ++j) {
        const int nl = wc * 32 + j * 16 + lcol;
        const float bvl = bias[n0 + nl];
#pragma unroll
        for (int r = 0; r < 4; ++r) {
          const int ml = wr * 32 + i * 16 + lrow + r;
          T[nl * 72 + ml] = (bf16)(acc[i][j][r] + bvl);
        }
      }
    }
    __syncthreads();
    const int nr = t >> 2, mseg = (t & 3) << 4;
    const int b = m0 >> 9;
    uint4 v0 = *(const uint4*)&T[nr * 72 + mseg];
    uint4 v1 = *(const uint4*)&T[nr * 72 + mseg + 8];
    bf16* dst = vt16 + ((size_t)(b * 1024 + n0 + nr) * 512 + (m0 & 511) + mseg);
    *(uint4*)dst       = v0;
    *(uint4*)(dst + 8) = v1;
    return;
  }

#pragma unroll
  for (int i = 0; i < 2; ++i) {
#pragma unroll
    for (int j = 0; j < 2; ++j) {
      const int n = n0 + wc * 32 + j * 16 + lcol;
      const float bvl = bias[n];
#pragma unroll
      for (int r = 0; r < 4; ++r) {
        const int m = m0 + wr * 32 + i * 16 + lrow + r;
        const float val = acc[i][j][r] + bvl;
        const int b = m >> 9, ii = m & 511, h = n >> 7, dk = n & 127;
        const size_t idx = (((size_t)(b * 8 + h) * 512) + ii) * 128 + dk;
        if (sel == 0) { qf[idx] = val; q16[idx] = (bf16)val; }
        else          { k16[idx] = (bf16)val; }
      }
    }
  }
}

// =====================================================================
// qs_fat: blocks 0..1023 = QK^T MFMA (sc = q16 @ k16^T, overwrite);
//         block 1024     = sep/gating/loss.
// =====================================================================
__global__ __launch_bounds__(256)
void qs_fat(const bf16* __restrict__ Q, const bf16* __restrict__ Kb,
            float* __restrict__ scores,
            const float* __restrict__ qf, const float* __restrict__ hw,
            const int* __restrict__ sep_id, const float* __restrict__ hreg,
            float* __restrict__ g, float* __restrict__ loss_out)
{
  __shared__ bf16 As[64][72];
  __shared__ bf16 Bs[64][72];
  __shared__ float pool[16][4];
  __shared__ float spred[16][4];
  __shared__ float lbuf[16];
  __shared__ int sids[4];
  const int t = threadIdx.x;

  if (blockIdx.x >= 1024) {
    if (t < 4) sids[t] = sep_id[t];
    __syncthreads();
    {
      const int dot = t >> 2, sub = t & 3;
      const int bh = dot >> 2, n = dot & 3;
      const int b = bh >> 3, h = bh & 7;
      const int row = sids[n];
      const float* qp = qf + (((size_t)(b * 8 + h) * 512) + row) * 128 + sub * 32;
      const float* wp = hw + h * 128 + sub * 32;
      float s = 0.f;
#pragma unroll
      for (int dd = 0; dd < 32; ++dd) s = fmaf(qp[dd], wp[dd], s);
      s += __shfl_xor(s, 1);
      s += __shfl_xor(s, 2);
      if (sub == 0) pool[bh][n] = s;
    }
    __syncthreads();
    if (t < 16) {
      float pv[4];
#pragma unroll
      for (int n = 0; n < 4; ++n) pv[n] = pool[t][n];
      float mx = fmaxf(fmaxf(pv[0], pv[1]), fmaxf(pv[2], pv[3]));
      float sum = 0.f;
#pragma unroll
      for (int n = 0; n < 4; ++n) { pv[n] = expf(pv[n] - mx); sum += pv[n]; }
      const float inv = 1.f / sum;
      float maxp = 0.f, l2 = 0.f;
#pragma unroll
      for (int n = 0; n < 4; ++n) {
        const float pr = pv[n] * inv;
        spred[t][n] = pr;
        maxp = fmaxf(maxp, pr);
        const float tg = hreg[n];
        l2 += tg * (logf(tg) - logf(pr));
      }
      lbuf[t] = (1.f - maxp) / 16.f + l2 / 64.f;
    }
    __syncthreads();
    if (t == 0) {
      float L = 0.f;
#pragma unroll
      for (int r = 0; r < 16; ++r) L += lbuf[r];
      loss_out[0] = L;
    }
    for (int idx = t; idx < 16 * 512; idx += 256) {
      const int bh = idx >> 9, pp = idx & 511;
      float gg = 0.f;
#pragma unroll
      for (int n = 0; n < 4; ++n)
        gg += spred[bh][n] * (pp >= sids[n] ? 1.f : 0.f);
      g[idx] = gg;
    }
    return;
  }

  const int bh = blockIdx.x >> 6, tile = blockIdx.x & 63;
  const bf16* A = Q  + (size_t)bh * (512 * 128);
  const bf16* B = Kb + (size_t)bh * (512 * 128);
  float* C = scores + (size_t)bh * (512 * 512);
  const int m0 = (tile >> 3) << 6, n0 = (tile & 7) << 6;
  const int wave = t >> 6, lane = t & 63;
  const int wr = wave >> 1, wc = wave & 1;
  const int srow = t >> 2, skc = (t & 3) << 4;
  const int fr = lane & 15, kb = (lane >> 4) << 3;
  f32x4 acc[2][2];
#pragma unroll
  for (int i = 0; i < 2; ++i)
#pragma unroll
    for (int j = 0; j < 2; ++j) acc[i][j] = (f32x4){0.f, 0.f, 0.f, 0.f};

  const bf16* ap = A + (size_t)(m0 + srow) * 128 + skc;
  const bf16* bp = B + (size_t)(n0 + srow) * 128 + skc;
  uint4 a0 = *(const uint4*)ap, a1 = *(const uint4*)(ap + 8);
  uint4 b0 = *(const uint4*)bp, b1 = *(const uint4*)(bp + 8);
  for (int k0 = 0; k0 < 128; k0 += 64) {
    __syncthreads();
    *(uint4*)&As[srow][skc]     = a0; *(uint4*)&As[srow][skc + 8] = a1;
    *(uint4*)&Bs[srow][skc]     = b0; *(uint4*)&Bs[srow][skc + 8] = b1;
    __syncthreads();
    if (k0 == 0) {
      a0 = *(const uint4*)(ap + 64); a1 = *(const uint4*)(ap + 72);
      b0 = *(const uint4*)(bp + 64); b1 = *(const uint4*)(bp + 72);
    }
#pragma unroll
    for (int ks = 0; ks < 2; ++ks) {
      bf16x8 af[2], bff[2];
#pragma unroll
      for (int f = 0; f < 2; ++f) {
        af[f]  = *(const bf16x8*)&As[wr * 32 + f * 16 + fr][ks * 32 + kb];
        bff[f] = *(const bf16x8*)&Bs[wc * 32 + f * 16 + fr][ks * 32 + kb];
      }
#pragma unroll
      for (int i = 0; i < 2; ++i)
#pragma unroll
        for (int j = 0; j < 2; ++j)
          acc[i][j] = MFMA16(af[i], bff[j], acc[i][j]);
    }
  }
  const int lrow = (lane >> 4) << 2, lcol = lane & 15;
#pragma unroll
  for (int i = 0; i < 2; ++i)
#pragma unroll
    for (int j = 0; j < 2; ++j)
#pragma unroll
      for (int r = 0; r < 4; ++r) {
        const int m = m0 + wr * 32 + i * 16 + lrow + r;
        const int n = n0 + wc * 32 + j * 16 + lcol;
        C[(size_t)m * 512 + n] = acc[i][j][r];
      }
}

// =====================================================================
// relk_sm: per (b,i) block, 2-deep prefetched rk stream.
// Phase 1 (MFMA): rel[j,h] = rk[b,i] (512x128) @ q16(16x128)^T
// Phase 2: softmax((sc+rel)*SCALE, mask, factor) -> pb16.
// =====================================================================
__global__ __launch_bounds__(256)
void relk_sm(const bf16* __restrict__ q16, const float* __restrict__ rk,
             const float* __restrict__ sc, const int* __restrict__ mask,
             const float* __restrict__ g, bf16* __restrict__ pb)
{
  const int bi = blockIdx.x, b = bi >> 9, i = bi & 511;
  __shared__ float rel_[8 * 516];
  const int t = threadIdx.x;
  const int w = t >> 6, lane = t & 63;
  const int fr = lane & 15, fg = lane >> 4;

  bf16x8 bq[4];
#pragma unroll
  for (int kt = 0; kt < 4; ++kt) {
    if (fr < 8) {
      bq[kt] = *(const bf16x8*)&q16[(((size_t)(b * 8 + fr) * 512) + i) * 128
                                    + kt * 32 + fg * 8];
    } else {
#pragma unroll
      for (int e = 0; e < 8; ++e) bq[kt][e] = (bf16)0.f;
    }
  }

  const float* rkb = rk + (size_t)bi * 512 * 128;
  float4 a[8], an[8];
  {
    const float* rp = rkb + (size_t)(w * 16 + fr) * 128 + fg * 8;
#pragma unroll
    for (int kt = 0; kt < 4; ++kt) {
      a[kt * 2]     = *(const float4*)(rp + kt * 32);
      a[kt * 2 + 1] = *(const float4*)(rp + kt * 32 + 4);
    }
  }
  for (int c = 0; c < 8; ++c) {
    if (c + 1 < 8) {
      const float* rp = rkb + (size_t)((c + 1) * 64 + w * 16 + fr) * 128 + fg * 8;
#pragma unroll
      for (int kt = 0; kt < 4; ++kt) {
        an[kt * 2]     = *(const float4*)(rp + kt * 32);
        an[kt * 2 + 1] = *(const float4*)(rp + kt * 32 + 4);
      }
    }
    f32x4 acc = (f32x4){0.f, 0.f, 0.f, 0.f};
#pragma unroll
    for (int kt = 0; kt < 4; ++kt)
      acc = MFMA16(cvt8(a[kt * 2], a[kt * 2 + 1]), bq[kt], acc);
    const int jb = c * 64 + w * 16;
    if (fr < 8) {
#pragma unroll
      for (int r = 0; r < 4; ++r)
        rel_[fr * 516 + jb + fg * 4 + r] = acc[r];
    }
#pragma unroll
    for (int u = 0; u < 8; ++u) a[u] = an[u];
  }
  __syncthreads();

  const int h = t >> 5, ln = t & 31;
  const float* scrow = sc + (((size_t)(b * 8 + h) * 512) + i) * 512;
  const int* mrow = mask + ((size_t)(b * 512 + i)) * 512;
  const float* grow = g + (b * 8 + h) * 512;
  const float gi = grow[i];
  float s[16];
  float mx = -3.402823466e+38f;
#pragma unroll
  for (int k = 0; k < 16; ++k) {
    const int j = ln + (k << 5);
    float sv = (scrow[j] + rel_[h * 516 + j]) * SCALE;
    if (mrow[j] == 0) sv = -1.0e9f;
    const float fac = (j >= i) ? gi : grow[j];
    sv *= fac;
    s[k] = sv;
    mx = fmaxf(mx, sv);
  }
#pragma unroll
  for (int off = 16; off > 0; off >>= 1) mx = fmaxf(mx, __shfl_xor(mx, off));
  float sum = 0.f;
#pragma unroll
  for (int k = 0; k < 16; ++k) { const float e = __expf(s[k] - mx); s[k] = e; sum += e; }
#pragma unroll
  for (int off = 16; off > 0; off >>= 1) sum += __shfl_xor(sum, off);
  const float inv = 1.f / sum;
  bf16* prow = pb + (((size_t)(b * 8 + h) * 512) + i) * 512;
#pragma unroll
  for (int k = 0; k < 16; ++k) {
    const int j = ln + (k << 5);
    prow[j] = (bf16)(s[k] * inv);
  }
}

// =====================================================================
// relv_fat:
//  blocks 0..255    = PV MFMA (xb2 = p16 @ vt16, overwrite)
//  blocks 256..1279 = relv MFMA per (b,i), direct global A-frags with
//     2-deep prefetch; xa written via LDS-staged coalesced float4.
// =====================================================================
__global__ __launch_bounds__(256)
void relv_fat(const bf16* __restrict__ P, const bf16* __restrict__ VT,
              const float* __restrict__ rvg,
              float* __restrict__ xb2, float* __restrict__ xa)
{
  __shared__ __align__(16) char smem_raw[18432];
  const int t = threadIdx.x;

  if (blockIdx.x < 256) {
    bf16 (*As)[72] = (bf16(*)[72])&smem_raw[0];
    bf16 (*Bs)[72] = (bf16(*)[72])&smem_raw[9216];
    const int bh = blockIdx.x >> 4, tile = blockIdx.x & 15;
    const int b = bh >> 3, h = bh & 7;
    const bf16* A = P  + (size_t)bh * (512 * 512);
    const bf16* B = VT + (size_t)bh * (128 * 512);
    float* C = xb2 + (size_t)b * (512 * 1024) + h * 128;
    const int m0 = (tile >> 1) << 6, n0 = (tile & 1) << 6;
    const int wave = t >> 6, lane = t & 63;
    const int wr = wave >> 1, wc = wave & 1;
    const int srow = t >> 2, skc = (t & 3) << 4;
    const int fr = lane & 15, kb = (lane >> 4) << 3;
    f32x4 acc[2][2];
#pragma unroll
    for (int i = 0; i < 2; ++i)
#pragma unroll
      for (int j = 0; j < 2; ++j) acc[i][j] = (f32x4){0.f, 0.f, 0.f, 0.f};

    const bf16* ap = A + (size_t)(m0 + srow) * 512 + skc;
    const bf16* bp = B + (size_t)(n0 + srow) * 512 + skc;
    uint4 a0 = *(const uint4*)ap, a1 = *(const uint4*)(ap + 8);
    uint4 b0 = *(const uint4*)bp, b1 = *(const uint4*)(bp + 8);
    for (int k0 = 0; k0 < 512; k0 += 64) {
      __syncthreads();
      *(uint4*)&As[srow][skc]     = a0; *(uint4*)&As[srow][skc + 8] = a1;
      *(uint4*)&Bs[srow][skc]     = b0; *(uint4*)&Bs[srow][skc + 8] = b1;
      __syncthreads();
      if (k0 + 64 < 512) {
        a0 = *(const uint4*)(ap + k0 + 64); a1 = *(const uint4*)(ap + k0 + 72);
        b0 = *(const uint4*)(bp + k0 + 64); b1 = *(const uint4*)(bp + k0 + 72);
      }
#pragma unroll
      for (int ks = 0; ks < 2; ++ks) {
        bf16x8 af[2], bff[2];
#pragma unroll
        for (int f = 0; f < 2; ++f) {
          af[f]  = *(const bf16x8*)&As[wr * 32 + f * 16 + fr][ks * 32 + kb];
          bff[f] = *(const bf16x8*)&Bs[wc * 32 + f * 16 + fr][ks * 32 + kb];
        }
#pragma unroll
        for (int i = 0; i < 2; ++i)
#pragma unroll
          for (int j = 0; j < 2; ++j)
            acc[i][j] = MFMA16(af[i], bff[j], acc[i][j]);
      }
    }
    const int lrow = (lane >> 4) << 2, lcol = lane & 15;
#pragma unroll
    for (int i = 0; i < 2; ++i)
#pragma unroll
      for (int j = 0; j < 2; ++j)
#pragma unroll
        for (int r = 0; r < 4; ++r) {
          const int m = m0 + wr * 32 + i * 16 + lrow + r;
          const int n = n0 + wc * 32 + j * 16 + lcol;
          C[(size_t)m * 1024 + n] = acc[i][j][r];
        }
    return;
  }

  // ---- relv MFMA, direct A-frags with prefetch ----
  const int bi = blockIdx.x - 256, b = bi >> 9, i = bi & 511;
  bf16* p_lds = (bf16*)&smem_raw[0];       // [8][536]
  const int w = t >> 6, lane = t & 63;
  const int fr = lane & 15, fg = lane >> 4;

  {
    const int h = t >> 5, j0 = (t & 31) << 4;
    const bf16* src = P + (((size_t)(b * 8 + h) * 512) + i) * 512 + j0;
    const uint4 v0 = *(const uint4*)src;
    const uint4 v1 = *(const uint4*)(src + 8);
    *(uint4*)&p_lds[h * 536 + j0]     = v0;
    *(uint4*)&p_lds[h * 536 + j0 + 8] = v1;
  }
  __syncthreads();

  const int ct0 = w * 2, ct1 = w * 2 + 1;   // d-tiles (16 d each)
  f32x4 acc0 = (f32x4){0.f, 0.f, 0.f, 0.f};
  f32x4 acc1 = (f32x4){0.f, 0.f, 0.f, 0.f};
  const float* rvb = rvg + (size_t)bi * 512 * 128;

  float a0v[8], a1v[8], a0n[8], a1n[8];
  {
    const int jb = fg * 8;
#pragma unroll
    for (int e = 0; e < 8; ++e) {
      const float* col = rvb + (size_t)(jb + e) * 128 + fr;
      a0v[e] = col[ct0 * 16];
      a1v[e] = col[ct1 * 16];
    }
  }
  for (int js = 0; js < 16; ++js) {
    if (js + 1 < 16) {
      const int jb = (js + 1) * 32 + fg * 8;
#pragma unroll
      for (int e = 0; e < 8; ++e) {
        const float* col = rvb + (size_t)(jb + e) * 128 + fr;
        a0n[e] = col[ct0 * 16];
        a1n[e] = col[ct1 * 16];
      }
    }
    const int jb = js * 32 + fg * 8;
    const bf16x8 bp = *(const bf16x8*)&p_lds[(fr & 7) * 536 + jb];
    bf16x8 af0, af1;
#pragma unroll
    for (int e = 0; e < 8; ++e) { af0[e] = (bf16)a0v[e]; af1[e] = (bf16)a1v[e]; }
    acc0 = MFMA16(af0, bp, acc0);
    acc1 = MFMA16(af1, bp, acc1);
#pragma unroll
    for (int e = 0; e < 8; ++e) { a0v[e] = a0n[e]; a1v[e] = a1n[e]; }
  }

  // stage D[d][h] -> LDS, then coalesced float4 write
  float* xs = (float*)&smem_raw[0];        // [8][128] fp32, 4 KB
  __syncthreads();                          // p_lds reads done
  if (fr < 8) {
#pragma unroll
    for (int r = 0; r < 4; ++r) {
      xs[fr * 128 + ct0 * 16 + fg * 4 + r] = acc0[r];
      xs[fr * 128 + ct1 * 16 + fg * 4 + r] = acc1[r];
    }
  }
  __syncthreads();
  {
    const int h = t >> 5, d0 = (t & 31) << 2;
    const f32x4 v = *(const f32x4*)&xs[h * 128 + d0];
    *(f32x4*)&xa[((size_t)(b * 512 + i)) * 1024 + h * 128 + d0] = v;
  }
}

// =====================================================================
// Output projection, LDS double-buffer: Cf = (xa + xb2) @ Wo16^T + bias
// =====================================================================
__global__ __launch_bounds__(256)
void proj_out2(const float* __restrict__ A, const float* __restrict__ A2,
               const bf16* __restrict__ W16,
               const float* __restrict__ bias, float* __restrict__ Cf)
{
  __shared__ bf16 As[2][64][72];
  __shared__ bf16 Bs[2][64][72];
  const int t = threadIdx.x;
  const int m0 = (blockIdx.x >> 4) << 6;
  const int n0 = (blockIdx.x & 15) << 6;
  const int wave = t >> 6, lane = t & 63;
  const int wr = wave >> 1, wc = wave & 1;
  const int srow = t >> 2, skc = (t & 3) << 4;
  const float* Ap  = A   + (size_t)(m0 + srow) * 1024 + skc;
  const float* A2p = A2  + (size_t)(m0 + srow) * 1024 + skc;
  const bf16*  Wp  = W16 + (size_t)(n0 + srow) * 1024 + skc;
  const int fr = lane & 15, kb = (lane >> 4) << 3;
  f32x4 acc[2][2];
#pragma unroll
  for (int i = 0; i < 2; ++i)
#pragma unroll
    for (int j = 0; j < 2; ++j) acc[i][j] = (f32x4){0.f, 0.f, 0.f, 0.f};

  float4 a4[4], a4n[4];
  uint4 b0 = *(const uint4*)Wp, b1 = *(const uint4*)(Wp + 8);
  uint4 b0n, b1n;
#pragma unroll
  for (int u = 0; u < 4; ++u) {
    const float4 x1 = *(const float4*)(Ap + u * 4);
    const float4 x2 = *(const float4*)(A2p + u * 4);
    a4[u] = make_float4(x1.x + x2.x, x1.y + x2.y, x1.z + x2.z, x1.w + x2.w);
  }
  for (int k0 = 0; k0 < 1024; k0 += 64) {
    const int buf = (k0 >> 6) & 1;
    *(bf16x8*)&As[buf][srow][skc]     = cvt8(a4[0], a4[1]);
    *(bf16x8*)&As[buf][srow][skc + 8] = cvt8(a4[2], a4[3]);
    *(uint4*)&Bs[buf][srow][skc]      = b0;
    *(uint4*)&Bs[buf][srow][skc + 8]  = b1;
    if (k0 + 64 < 1024) {
#pragma unroll
      for (int u = 0; u < 4; ++u) {
        const float4 x1 = *(const float4*)(Ap + k0 + 64 + u * 4);
        const float4 x2 = *(const float4*)(A2p + k0 + 64 + u * 4);
        a4n[u] = make_float4(x1.x + x2.x, x1.y + x2.y, x1.z + x2.z, x1.w + x2.w);
      }
      b0n = *(const uint4*)(Wp + k0 + 64);
      b1n = *(const uint4*)(Wp + k0 + 72);
    }
    __syncthreads();
#pragma unroll
    for (int ks = 0; ks < 2; ++ks) {
      bf16x8 af[2], bff[2];
#pragma unroll
      for (int f = 0; f < 2; ++f) {
        af[f]  = *(const bf16x8*)&As[buf][wr * 32 + f * 16 + fr][ks * 32 + kb];
        bff[f] = *(const bf16x8*)&Bs[buf][wc * 32 + f * 16 + fr][ks * 32 + kb];
      }
#pragma unroll
      for (int i = 0; i < 2; ++i)
#pragma unroll
        for (int j = 0; j < 2; ++j)
          acc[i][j] = MFMA16(af[i], bff[j], acc[i][j]);
    }
#pragma unroll
    for (int u = 0; u < 4; ++u) a4[u] = a4n[u];
    b0 = b0n; b1 = b1n;
  }
  const int lrow = (lane >> 4) << 2, lcol = lane & 15;
#pragma unroll
  for (int i = 0; i < 2; ++i) {
#pragma unroll
    for (int j = 0; j < 2; ++j) {
      const int n = n0 + wc * 32 + j * 16 + lcol;
      const float bvl = bias[n];
#pragma unroll
      for (int r = 0; r < 4; ++r) {
        const int m = m0 + wr * 32 + i * 16 + lrow + r;
        Cf[(size_t)m * 1024 + n] = acc[i][j][r] + bvl;
      }
    }
  }
}

// =====================================================================
extern "C" void kernel_launch(void* const* d_in, const int* in_sizes, int n_in,
                              void* d_out, int out_size, void* d_ws, size_t ws_size,
                              hipStream_t stream)
{
  const float* query = (const float*)d_in[0];
  const float* key   = (const float*)d_in[1];
  const float* value = (const float*)d_in[2];
  const float* rk    = (const float*)d_in[3];
  const float* rv    = (const float*)d_in[4];
  const int*   mask  = (const int*)d_in[5];
  const int*   sep   = (const int*)d_in[6];
  const float* hreg  = (const float*)d_in[7];
  const float* Wq    = (const float*)d_in[8];
  const float* bq    = (const float*)d_in[9];
  const float* Wk    = (const float*)d_in[10];
  const float* bk    = (const float*)d_in[11];
  const float* Wv    = (const float*)d_in[12];
  const float* bv    = (const float*)d_in[13];
  const float* Wo    = (const float*)d_in[14];
  const float* bo    = (const float*)d_in[15];
  const float* hw    = (const float*)d_in[16];
  float* out = (float*)d_out;

  float* ws  = (float*)d_ws;
  float* qb  = ws;                           // 1,048,576 f32
  float* sc  = qb + 1048576;                 // 4,194,304 f32
  float* xa  = sc + 4194304;                 // 1,048,576 f32
  float* xb2 = xa + 1048576;                 // 1,048,576 f32
  float* gb  = xb2 + 1048576;                //     8,192 f32
  bf16* qb16 = (bf16*)(gb + 8192);           // 1,048,576 bf16
  bf16* kb16 = qb16 + 1048576;               // 1,048,576 bf16
  bf16* vt16 = kb16 + 1048576;               // 1,048,576 bf16
  bf16* pb16 = vt16 + 1048576;               // 4,194,304 bf16
  // conversion buffers: first 4 alias pb16 (dead until relk_sm writes it)
  bf16* qA16 = pb16;
  bf16* kA16 = qA16 + 1048576;
  bf16* vA16 = kA16 + 1048576;
  bf16* Wq16 = vA16 + 1048576;
  bf16* Wk16 = pb16 + 4194304;
  bf16* Wv16 = Wk16 + 1048576;
  bf16* Wo16 = Wv16 + 1048576;

  cvt_bf16<<<dim3(512, 7), 256, 0, stream>>>(query, key, value, Wq, Wk, Wv, Wo,
                                             qA16, kA16, vA16, Wq16, Wk16, Wv16,
                                             Wo16);
  proj3_mfma2<<<dim3(256, 3), 256, 0, stream>>>(qA16, kA16, vA16,
                                                Wq16, Wk16, Wv16, bq, bk, bv,
                                                qb, qb16, kb16, vt16);
  qs_fat<<<dim3(1025), 256, 0, stream>>>(qb16, kb16, sc,
                                         qb, hw, sep, hreg, gb, out + 1048576);
  relk_sm<<<dim3(1024), 256, 0, stream>>>(qb16, rk, sc, mask, gb, pb16);
  relv_fat<<<dim3(1280), 256, 0, stream>>>(pb16, vt16, rv, xb2, xa);
  proj_out2<<<dim3(256), 256, 0, stream>>>(xa, xb2, Wo16, bo, out);
}

// Round 13
// 170.113 us; speedup vs baseline: 2.6154x; 1.0193x over previous
//
#include <hip/hip_runtime.h>

static constexpr float SCALE = 0.08838834764831845f; // 1/sqrt(128)

typedef __bf16 bf16;
typedef __bf16 bf16x8 __attribute__((ext_vector_type(8)));
typedef float  f32x4  __attribute__((ext_vector_type(4)));

#define MFMA16(a, b, c) __builtin_amdgcn_mfma_f32_16x16x32_bf16((a), (b), (c), 0, 0, 0)

__device__ inline bf16x8 cvt8(const float4& x, const float4& y) {
  bf16x8 r;
  r[0] = (bf16)x.x; r[1] = (bf16)x.y; r[2] = (bf16)x.z; r[3] = (bf16)x.w;
  r[4] = (bf16)y.x; r[5] = (bf16)y.y; r[6] = (bf16)y.z; r[7] = (bf16)y.w;
  return r;
}

// =====================================================================
// cvt_bf16: convert 7 fp32 tensors (1M elements each) to bf16.
// =====================================================================
__global__ __launch_bounds__(256)
void cvt_bf16(const float* __restrict__ s0, const float* __restrict__ s1,
              const float* __restrict__ s2, const float* __restrict__ s3,
              const float* __restrict__ s4, const float* __restrict__ s5,
              const float* __restrict__ s6,
              bf16* __restrict__ d0, bf16* __restrict__ d1,
              bf16* __restrict__ d2, bf16* __restrict__ d3,
              bf16* __restrict__ d4, bf16* __restrict__ d5,
              bf16* __restrict__ d6)
{
  const int sel = blockIdx.y;
  const float* src = sel == 0 ? s0 : sel == 1 ? s1 : sel == 2 ? s2 :
                     sel == 3 ? s3 : sel == 4 ? s4 : sel == 5 ? s5 : s6;
  bf16* dst = sel == 0 ? d0 : sel == 1 ? d1 : sel == 2 ? d2 :
              sel == 3 ? d3 : sel == 4 ? d4 : sel == 5 ? d5 : d6;
  const size_t idx = ((size_t)blockIdx.x * 256 + threadIdx.x) * 8;
  const float4 a = *(const float4*)(src + idx);
  const float4 b = *(const float4*)(src + idx + 4);
  *(bf16x8*)(dst + idx) = cvt8(a, b);
}

// =====================================================================
// Batched projection GEMM, pure bf16, LDS double-buffer.
// sel==0 (q): bf16 q16 in [b,h,i,dk]
// sel==1 (k): bf16 k16 in [b,h,i,dk]
// sel==2 (v): bf16 vt16 TRANSPOSED [b,h,dk,i] via LDS-transposed epilogue
// =====================================================================
__global__ __launch_bounds__(256)
void proj3_mfma2(const bf16* __restrict__ Aq, const bf16* __restrict__ Ak,
                 const bf16* __restrict__ Av,
                 const bf16* __restrict__ Wq, const bf16* __restrict__ Wk,
                 const bf16* __restrict__ Wv,
                 const float* __restrict__ bq, const float* __restrict__ bk,
                 const float* __restrict__ bv,
                 bf16* __restrict__ q16,
                 bf16* __restrict__ k16, bf16* __restrict__ vt16)
{
  const int sel = blockIdx.y;
  const bf16* A     = sel == 0 ? Aq : (sel == 1 ? Ak : Av);
  const bf16* W     = sel == 0 ? Wq : (sel == 1 ? Wk : Wv);
  const float* bias = sel == 0 ? bq : (sel == 1 ? bk : bv);
  bf16* Cb          = sel == 0 ? q16 : k16;

  __shared__ bf16 As[2][64][72];
  __shared__ bf16 Bs[2][64][72];
  const int t = threadIdx.x;
  const int m0 = (blockIdx.x >> 4) << 6;
  const int n0 = (blockIdx.x & 15) << 6;
  const int wave = t >> 6, lane = t & 63;
  const int wr = wave >> 1, wc = wave & 1;
  const int srow = t >> 2, skc = (t & 3) << 4;
  const bf16* Ap = A + (size_t)(m0 + srow) * 1024 + skc;
  const bf16* Wp = W + (size_t)(n0 + srow) * 1024 + skc;
  const int fr = lane & 15, kb = (lane >> 4) << 3;
  f32x4 acc[2][2];
#pragma unroll
  for (int i = 0; i < 2; ++i)
#pragma unroll
    for (int j = 0; j < 2; ++j) acc[i][j] = (f32x4){0.f, 0.f, 0.f, 0.f};

  uint4 a0 = *(const uint4*)Ap, a1 = *(const uint4*)(Ap + 8);
  uint4 b0 = *(const uint4*)Wp, b1 = *(const uint4*)(Wp + 8);
  uint4 a0n, a1n, b0n, b1n;
  for (int k0 = 0; k0 < 1024; k0 += 64) {
    const int buf = (k0 >> 6) & 1;
    *(uint4*)&As[buf][srow][skc]     = a0; *(uint4*)&As[buf][srow][skc + 8] = a1;
    *(uint4*)&Bs[buf][srow][skc]     = b0; *(uint4*)&Bs[buf][srow][skc + 8] = b1;
    if (k0 + 64 < 1024) {
      a0n = *(const uint4*)(Ap + k0 + 64); a1n = *(const uint4*)(Ap + k0 + 72);
      b0n = *(const uint4*)(Wp + k0 + 64); b1n = *(const uint4*)(Wp + k0 + 72);
    }
    __syncthreads();
#pragma unroll
    for (int ks = 0; ks < 2; ++ks) {
      bf16x8 af[2], bff[2];
#pragma unroll
      for (int f = 0; f < 2; ++f) {
        af[f]  = *(const bf16x8*)&As[buf][wr * 32 + f * 16 + fr][ks * 32 + kb];
        bff[f] = *(const bf16x8*)&Bs[buf][wc * 32 + f * 16 + fr][ks * 32 + kb];
      }
#pragma unroll
      for (int i = 0; i < 2; ++i)
#pragma unroll
        for (int j = 0; j < 2; ++j)
          acc[i][j] = MFMA16(af[i], bff[j], acc[i][j]);
    }
    a0 = a0n; a1 = a1n; b0 = b0n; b1 = b1n;
  }
  const int lrow = (lane >> 4) << 2, lcol = lane & 15;

  if (sel == 2) {
    // LDS-transposed epilogue: T[n_local][m_local] bf16, stride 72
    bf16* T = &As[0][0][0];
    __syncthreads();                  // all MFMA LDS reads done
#pragma unroll
    for (int i = 0; i < 2; ++i) {
#pragma unroll
      for (int j = 0; j < 2; ++j) {
        const int nl = wc * 32 + j * 16 + lcol;
        const float bvl = bias[n0 + nl];
#pragma unroll
        for (int r = 0; r < 4; ++r) {
          const int ml = wr * 32 + i * 16 + lrow + r;
          T[nl * 72 + ml] = (bf16)(acc[i][j][r] + bvl);
        }
      }
    }
    __syncthreads();
    const int nr = t >> 2, mseg = (t & 3) << 4;
    const int b = m0 >> 9;
    uint4 v0 = *(const uint4*)&T[nr * 72 + mseg];
    uint4 v1 = *(const uint4*)&T[nr * 72 + mseg + 8];
    bf16* dst = vt16 + ((size_t)(b * 1024 + n0 + nr) * 512 + (m0 & 511) + mseg);
    *(uint4*)dst       = v0;
    *(uint4*)(dst + 8) = v1;
    return;
  }

#pragma unroll
  for (int i = 0; i < 2; ++i) {
#pragma unroll
    for (int j = 0; j < 2; ++j) {
      const int n = n0 + wc * 32 + j * 16 + lcol;
      const float bvl = bias[n];
#pragma unroll
      for (int r = 0; r < 4; ++r) {
        const int m = m0 + wr * 32 + i * 16 + lrow + r;
        const float val = acc[i][j][r] + bvl;
        const int b = m >> 9, ii = m & 511, h = n >> 7, dk = n & 127;
        const size_t idx = (((size_t)(b * 8 + h) * 512) + ii) * 128 + dk;
        Cb[idx] = (bf16)val;
      }
    }
  }
}

// =====================================================================
// qs_fat: blocks 0..1023 = QK^T MFMA (sc16 = q16 @ k16^T, bf16 out);
//         block 1024     = sep/gating/loss (reads q16).
// =====================================================================
__global__ __launch_bounds__(256)
void qs_fat(const bf16* __restrict__ Q, const bf16* __restrict__ Kb,
            bf16* __restrict__ scores,
            const float* __restrict__ hw,
            const int* __restrict__ sep_id, const float* __restrict__ hreg,
            float* __restrict__ g, float* __restrict__ loss_out)
{
  __shared__ bf16 As[64][72];
  __shared__ bf16 Bs[64][72];
  __shared__ float pool[16][4];
  __shared__ float spred[16][4];
  __shared__ float lbuf[16];
  __shared__ int sids[4];
  const int t = threadIdx.x;

  if (blockIdx.x >= 1024) {
    if (t < 4) sids[t] = sep_id[t];
    __syncthreads();
    {
      const int dot = t >> 2, sub = t & 3;
      const int bh = dot >> 2, n = dot & 3;
      const int b = bh >> 3, h = bh & 7;
      const int row = sids[n];
      const bf16* qp = Q + (((size_t)(b * 8 + h) * 512) + row) * 128 + sub * 32;
      const float* wp = hw + h * 128 + sub * 32;
      float s = 0.f;
#pragma unroll
      for (int dd = 0; dd < 32; ++dd) s = fmaf((float)qp[dd], wp[dd], s);
      s += __shfl_xor(s, 1);
      s += __shfl_xor(s, 2);
      if (sub == 0) pool[bh][n] = s;
    }
    __syncthreads();
    if (t < 16) {
      float pv[4];
#pragma unroll
      for (int n = 0; n < 4; ++n) pv[n] = pool[t][n];
      float mx = fmaxf(fmaxf(pv[0], pv[1]), fmaxf(pv[2], pv[3]));
      float sum = 0.f;
#pragma unroll
      for (int n = 0; n < 4; ++n) { pv[n] = expf(pv[n] - mx); sum += pv[n]; }
      const float inv = 1.f / sum;
      float maxp = 0.f, l2 = 0.f;
#pragma unroll
      for (int n = 0; n < 4; ++n) {
        const float pr = pv[n] * inv;
        spred[t][n] = pr;
        maxp = fmaxf(maxp, pr);
        const float tg = hreg[n];
        l2 += tg * (logf(tg) - logf(pr));
      }
      lbuf[t] = (1.f - maxp) / 16.f + l2 / 64.f;
    }
    __syncthreads();
    if (t == 0) {
      float L = 0.f;
#pragma unroll
      for (int r = 0; r < 16; ++r) L += lbuf[r];
      loss_out[0] = L;
    }
    for (int idx = t; idx < 16 * 512; idx += 256) {
      const int bh = idx >> 9, pp = idx & 511;
      float gg = 0.f;
#pragma unroll
      for (int n = 0; n < 4; ++n)
        gg += spred[bh][n] * (pp >= sids[n] ? 1.f : 0.f);
      g[idx] = gg;
    }
    return;
  }

  const int bh = blockIdx.x >> 6, tile = blockIdx.x & 63;
  const bf16* A = Q  + (size_t)bh * (512 * 128);
  const bf16* B = Kb + (size_t)bh * (512 * 128);
  bf16* C = scores + (size_t)bh * (512 * 512);
  const int m0 = (tile >> 3) << 6, n0 = (tile & 7) << 6;
  const int wave = t >> 6, lane = t & 63;
  const int wr = wave >> 1, wc = wave & 1;
  const int srow = t >> 2, skc = (t & 3) << 4;
  const int fr = lane & 15, kb = (lane >> 4) << 3;
  f32x4 acc[2][2];
#pragma unroll
  for (int i = 0; i < 2; ++i)
#pragma unroll
    for (int j = 0; j < 2; ++j) acc[i][j] = (f32x4){0.f, 0.f, 0.f, 0.f};

  const bf16* ap = A + (size_t)(m0 + srow) * 128 + skc;
  const bf16* bp = B + (size_t)(n0 + srow) * 128 + skc;
  uint4 a0 = *(const uint4*)ap, a1 = *(const uint4*)(ap + 8);
  uint4 b0 = *(const uint4*)bp, b1 = *(const uint4*)(bp + 8);
  for (int k0 = 0; k0 < 128; k0 += 64) {
    __syncthreads();
    *(uint4*)&As[srow][skc]     = a0; *(uint4*)&As[srow][skc + 8] = a1;
    *(uint4*)&Bs[srow][skc]     = b0; *(uint4*)&Bs[srow][skc + 8] = b1;
    __syncthreads();
    if (k0 == 0) {
      a0 = *(const uint4*)(ap + 64); a1 = *(const uint4*)(ap + 72);
      b0 = *(const uint4*)(bp + 64); b1 = *(const uint4*)(bp + 72);
    }
#pragma unroll
    for (int ks = 0; ks < 2; ++ks) {
      bf16x8 af[2], bff[2];
#pragma unroll
      for (int f = 0; f < 2; ++f) {
        af[f]  = *(const bf16x8*)&As[wr * 32 + f * 16 + fr][ks * 32 + kb];
        bff[f] = *(const bf16x8*)&Bs[wc * 32 + f * 16 + fr][ks * 32 + kb];
      }
#pragma unroll
      for (int i = 0; i < 2; ++i)
#pragma unroll
        for (int j = 0; j < 2; ++j)
          acc[i][j] = MFMA16(af[i], bff[j], acc[i][j]);
    }
  }
  const int lrow = (lane >> 4) << 2, lcol = lane & 15;
#pragma unroll
  for (int i = 0; i < 2; ++i)
#pragma unroll
    for (int j = 0; j < 2; ++j)
#pragma unroll
      for (int r = 0; r < 4; ++r) {
        const int m = m0 + wr * 32 + i * 16 + lrow + r;
        const int n = n0 + wc * 32 + j * 16 + lcol;
        C[(size_t)m * 512 + n] = (bf16)acc[i][j][r];
      }
}

// =====================================================================
// relk_sm: per (b,i) block, 2-deep prefetched rk stream.
// Phase 1 (MFMA): rel[j,h] = rk[b,i] (512x128) @ q16(16x128)^T
// Phase 2: softmax((sc16+rel)*SCALE, mask, factor) -> pb16.
// =====================================================================
__global__ __launch_bounds__(256)
void relk_sm(const bf16* __restrict__ q16, const float* __restrict__ rk,
             const bf16* __restrict__ sc, const int* __restrict__ mask,
             const float* __restrict__ g, bf16* __restrict__ pb)
{
  const int bi = blockIdx.x, b = bi >> 9, i = bi & 511;
  __shared__ float rel_[8 * 516];
  const int t = threadIdx.x;
  const int w = t >> 6, lane = t & 63;
  const int fr = lane & 15, fg = lane >> 4;

  bf16x8 bq[4];
#pragma unroll
  for (int kt = 0; kt < 4; ++kt) {
    if (fr < 8) {
      bq[kt] = *(const bf16x8*)&q16[(((size_t)(b * 8 + fr) * 512) + i) * 128
                                    + kt * 32 + fg * 8];
    } else {
#pragma unroll
      for (int e = 0; e < 8; ++e) bq[kt][e] = (bf16)0.f;
    }
  }

  const float* rkb = rk + (size_t)bi * 512 * 128;
  float4 a[8], an[8];
  {
    const float* rp = rkb + (size_t)(w * 16 + fr) * 128 + fg * 8;
#pragma unroll
    for (int kt = 0; kt < 4; ++kt) {
      a[kt * 2]     = *(const float4*)(rp + kt * 32);
      a[kt * 2 + 1] = *(const float4*)(rp + kt * 32 + 4);
    }
  }
  for (int c = 0; c < 8; ++c) {
    if (c + 1 < 8) {
      const float* rp = rkb + (size_t)((c + 1) * 64 + w * 16 + fr) * 128 + fg * 8;
#pragma unroll
      for (int kt = 0; kt < 4; ++kt) {
        an[kt * 2]     = *(const float4*)(rp + kt * 32);
        an[kt * 2 + 1] = *(const float4*)(rp + kt * 32 + 4);
      }
    }
    f32x4 acc = (f32x4){0.f, 0.f, 0.f, 0.f};
#pragma unroll
    for (int kt = 0; kt < 4; ++kt)
      acc = MFMA16(cvt8(a[kt * 2], a[kt * 2 + 1]), bq[kt], acc);
    const int jb = c * 64 + w * 16;
    if (fr < 8) {
#pragma unroll
      for (int r = 0; r < 4; ++r)
        rel_[fr * 516 + jb + fg * 4 + r] = acc[r];
    }
#pragma unroll
    for (int u = 0; u < 8; ++u) a[u] = an[u];
  }
  __syncthreads();

  const int h = t >> 5, ln = t & 31;
  const bf16* scrow = sc + (((size_t)(b * 8 + h) * 512) + i) * 512;
  const int* mrow = mask + ((size_t)(b * 512 + i)) * 512;
  const float* grow = g + (b * 8 + h) * 512;
  const float gi = grow[i];
  float s[16];
  float mx = -3.402823466e+38f;
#pragma unroll
  for (int k = 0; k < 16; ++k) {
    const int j = ln + (k << 5);
    float sv = ((float)scrow[j] + rel_[h * 516 + j]) * SCALE;
    if (mrow[j] == 0) sv = -1.0e9f;
    const float fac = (j >= i) ? gi : grow[j];
    sv *= fac;
    s[k] = sv;
    mx = fmaxf(mx, sv);
  }
#pragma unroll
  for (int off = 16; off > 0; off >>= 1) mx = fmaxf(mx, __shfl_xor(mx, off));
  float sum = 0.f;
#pragma unroll
  for (int k = 0; k < 16; ++k) { const float e = __expf(s[k] - mx); s[k] = e; sum += e; }
#pragma unroll
  for (int off = 16; off > 0; off >>= 1) sum += __shfl_xor(sum, off);
  const float inv = 1.f / sum;
  bf16* prow = pb + (((size_t)(b * 8 + h) * 512) + i) * 512;
#pragma unroll
  for (int k = 0; k < 16; ++k) {
    const int j = ln + (k << 5);
    prow[j] = (bf16)(s[k] * inv);
  }
}

// =====================================================================
// relv_fat:
//  blocks 0..255    = PV MFMA (xb2 = p16 @ vt16, overwrite)
//  blocks 256..1279 = relv MFMA per (b,i), direct global A-frags with
//     2-deep prefetch; xa written via LDS-staged coalesced float4.
// =====================================================================
__global__ __launch_bounds__(256)
void relv_fat(const bf16* __restrict__ P, const bf16* __restrict__ VT,
              const float* __restrict__ rvg,
              float* __restrict__ xb2, float* __restrict__ xa)
{
  __shared__ __align__(16) char smem_raw[18432];
  const int t = threadIdx.x;

  if (blockIdx.x < 256) {
    bf16 (*As)[72] = (bf16(*)[72])&smem_raw[0];
    bf16 (*Bs)[72] = (bf16(*)[72])&smem_raw[9216];
    const int bh = blockIdx.x >> 4, tile = blockIdx.x & 15;
    const int b = bh >> 3, h = bh & 7;
    const bf16* A = P  + (size_t)bh * (512 * 512);
    const bf16* B = VT + (size_t)bh * (128 * 512);
    float* C = xb2 + (size_t)b * (512 * 1024) + h * 128;
    const int m0 = (tile >> 1) << 6, n0 = (tile & 1) << 6;
    const int wave = t >> 6, lane = t & 63;
    const int wr = wave >> 1, wc = wave & 1;
    const int srow = t >> 2, skc = (t & 3) << 4;
    const int fr = lane & 15, kb = (lane >> 4) << 3;
    f32x4 acc[2][2];
#pragma unroll
    for (int i = 0; i < 2; ++i)
#pragma unroll
      for (int j = 0; j < 2; ++j) acc[i][j] = (f32x4){0.f, 0.f, 0.f, 0.f};

    const bf16* ap = A + (size_t)(m0 + srow) * 512 + skc;
    const bf16* bp = B + (size_t)(n0 + srow) * 512 + skc;
    uint4 a0 = *(const uint4*)ap, a1 = *(const uint4*)(ap + 8);
    uint4 b0 = *(const uint4*)bp, b1 = *(const uint4*)(bp + 8);
    for (int k0 = 0; k0 < 512; k0 += 64) {
      __syncthreads();
      *(uint4*)&As[srow][skc]     = a0; *(uint4*)&As[srow][skc + 8] = a1;
      *(uint4*)&Bs[srow][skc]     = b0; *(uint4*)&Bs[srow][skc + 8] = b1;
      __syncthreads();
      if (k0 + 64 < 512) {
        a0 = *(const uint4*)(ap + k0 + 64); a1 = *(const uint4*)(ap + k0 + 72);
        b0 = *(const uint4*)(bp + k0 + 64); b1 = *(const uint4*)(bp + k0 + 72);
      }
#pragma unroll
      for (int ks = 0; ks < 2; ++ks) {
        bf16x8 af[2], bff[2];
#pragma unroll
        for (int f = 0; f < 2; ++f) {
          af[f]  = *(const bf16x8*)&As[wr * 32 + f * 16 + fr][ks * 32 + kb];
          bff[f] = *(const bf16x8*)&Bs[wc * 32 + f * 16 + fr][ks * 32 + kb];
        }
#pragma unroll
        for (int i = 0; i < 2; ++i)
#pragma unroll
          for (int j = 0; j < 2; ++j)
            acc[i][j] = MFMA16(af[i], bff[j], acc[i][j]);
      }
    }
    const int lrow = (lane >> 4) << 2, lcol = lane & 15;
#pragma unroll
    for (int i = 0; i < 2; ++i)
#pragma unroll
      for (int j = 0; j < 2; ++j)
#pragma unroll
        for (int r = 0; r < 4; ++r) {
          const int m = m0 + wr * 32 + i * 16 + lrow + r;
          const int n = n0 + wc * 32 + j * 16 + lcol;
          C[(size_t)m * 1024 + n] = acc[i][j][r];
        }
    return;
  }

  // ---- relv MFMA, direct A-frags with prefetch ----
  const int bi = blockIdx.x - 256, b = bi >> 9, i = bi & 511;
  bf16* p_lds = (bf16*)&smem_raw[0];       // [8][536]
  const int w = t >> 6, lane = t & 63;
  const int fr = lane & 15, fg = lane >> 4;

  {
    const int h = t >> 5, j0 = (t & 31) << 4;
    const bf16* src = P + (((size_t)(b * 8 + h) * 512) + i) * 512 + j0;
    const uint4 v0 = *(const uint4*)src;
    const uint4 v1 = *(const uint4*)(src + 8);
    *(uint4*)&p_lds[h * 536 + j0]     = v0;
    *(uint4*)&p_lds[h * 536 + j0 + 8] = v1;
  }
  __syncthreads();

  const int ct0 = w * 2, ct1 = w * 2 + 1;   // d-tiles (16 d each)
  f32x4 acc0 = (f32x4){0.f, 0.f, 0.f, 0.f};
  f32x4 acc1 = (f32x4){0.f, 0.f, 0.f, 0.f};
  const float* rvb = rvg + (size_t)bi * 512 * 128;

  float a0v[8], a1v[8], a0n[8], a1n[8];
  {
    const int jb = fg * 8;
#pragma unroll
    for (int e = 0; e < 8; ++e) {
      const float* col = rvb + (size_t)(jb + e) * 128 + fr;
      a0v[e] = col[ct0 * 16];
      a1v[e] = col[ct1 * 16];
    }
  }
  for (int js = 0; js < 16; ++js) {
    if (js + 1 < 16) {
      const int jb = (js + 1) * 32 + fg * 8;
#pragma unroll
      for (int e = 0; e < 8; ++e) {
        const float* col = rvb + (size_t)(jb + e) * 128 + fr;
        a0n[e] = col[ct0 * 16];
        a1n[e] = col[ct1 * 16];
      }
    }
    const int jb = js * 32 + fg * 8;
    const bf16x8 bp = *(const bf16x8*)&p_lds[(fr & 7) * 536 + jb];
    bf16x8 af0, af1;
#pragma unroll
    for (int e = 0; e < 8; ++e) { af0[e] = (bf16)a0v[e]; af1[e] = (bf16)a1v[e]; }
    acc0 = MFMA16(af0, bp, acc0);
    acc1 = MFMA16(af1, bp, acc1);
#pragma unroll
    for (int e = 0; e < 8; ++e) { a0v[e] = a0n[e]; a1v[e] = a1n[e]; }
  }

  // stage D[d][h] -> LDS, then coalesced float4 write
  float* xs = (float*)&smem_raw[0];        // [8][128] fp32, 4 KB
  __syncthreads();                          // p_lds reads done
  if (fr < 8) {
#pragma unroll
    for (int r = 0; r < 4; ++r) {
      xs[fr * 128 + ct0 * 16 + fg * 4 + r] = acc0[r];
      xs[fr * 128 + ct1 * 16 + fg * 4 + r] = acc1[r];
    }
  }
  __syncthreads();
  {
    const int h = t >> 5, d0 = (t & 31) << 2;
    const f32x4 v = *(const f32x4*)&xs[h * 128 + d0];
    *(f32x4*)&xa[((size_t)(b * 512 + i)) * 1024 + h * 128 + d0] = v;
  }
}

// =====================================================================
// Output projection, LDS double-buffer: Cf = (xa + xb2) @ Wo16^T + bias
// =====================================================================
__global__ __launch_bounds__(256)
void proj_out2(const float* __restrict__ A, const float* __restrict__ A2,
               const bf16* __restrict__ W16,
               const float* __restrict__ bias, float* __restrict__ Cf)
{
  __shared__ bf16 As[2][64][72];
  __shared__ bf16 Bs[2][64][72];
  const int t = threadIdx.x;
  const int m0 = (blockIdx.x >> 4) << 6;
  const int n0 = (blockIdx.x & 15) << 6;
  const int wave = t >> 6, lane = t & 63;
  const int wr = wave >> 1, wc = wave & 1;
  const int srow = t >> 2, skc = (t & 3) << 4;
  const float* Ap  = A   + (size_t)(m0 + srow) * 1024 + skc;
  const float* A2p = A2  + (size_t)(m0 + srow) * 1024 + skc;
  const bf16*  Wp  = W16 + (size_t)(n0 + srow) * 1024 + skc;
  const int fr = lane & 15, kb = (lane >> 4) << 3;
  f32x4 acc[2][2];
#pragma unroll
  for (int i = 0; i < 2; ++i)
#pragma unroll
    for (int j = 0; j < 2; ++j) acc[i][j] = (f32x4){0.f, 0.f, 0.f, 0.f};

  float4 a4[4], a4n[4];
  uint4 b0 = *(const uint4*)Wp, b1 = *(const uint4*)(Wp + 8);
  uint4 b0n, b1n;
#pragma unroll
  for (int u = 0; u < 4; ++u) {
    const float4 x1 = *(const float4*)(Ap + u * 4);
    const float4 x2 = *(const float4*)(A2p + u * 4);
    a4[u] = make_float4(x1.x + x2.x, x1.y + x2.y, x1.z + x2.z, x1.w + x2.w);
  }
  for (int k0 = 0; k0 < 1024; k0 += 64) {
    const int buf = (k0 >> 6) & 1;
    *(bf16x8*)&As[buf][srow][skc]     = cvt8(a4[0], a4[1]);
    *(bf16x8*)&As[buf][srow][skc + 8] = cvt8(a4[2], a4[3]);
    *(uint4*)&Bs[buf][srow][skc]      = b0;
    *(uint4*)&Bs[buf][srow][skc + 8]  = b1;
    if (k0 + 64 < 1024) {
#pragma unroll
      for (int u = 0; u < 4; ++u) {
        const float4 x1 = *(const float4*)(Ap + k0 + 64 + u * 4);
        const float4 x2 = *(const float4*)(A2p + k0 + 64 + u * 4);
        a4n[u] = make_float4(x1.x + x2.x, x1.y + x2.y, x1.z + x2.z, x1.w + x2.w);
      }
      b0n = *(const uint4*)(Wp + k0 + 64);
      b1n = *(const uint4*)(Wp + k0 + 72);
    }
    __syncthreads();
#pragma unroll
    for (int ks = 0; ks < 2; ++ks) {
      bf16x8 af[2], bff[2];
#pragma unroll
      for (int f = 0; f < 2; ++f) {
        af[f]  = *(const bf16x8*)&As[buf][wr * 32 + f * 16 + fr][ks * 32 + kb];
        bff[f] = *(const bf16x8*)&Bs[buf][wc * 32 + f * 16 + fr][ks * 32 + kb];
      }
#pragma unroll
      for (int i = 0; i < 2; ++i)
#pragma unroll
        for (int j = 0; j < 2; ++j)
          acc[i][j] = MFMA16(af[i], bff[j], acc[i][j]);
    }
#pragma unroll
    for (int u = 0; u < 4; ++u) a4[u] = a4n[u];
    b0 = b0n; b1 = b1n;
  }
  const int lrow = (lane >> 4) << 2, lcol = lane & 15;
#pragma unroll
  for (int i = 0; i < 2; ++i) {
#pragma unroll
    for (int j = 0; j < 2; ++j) {
      const int n = n0 + wc * 32 + j * 16 + lcol;
      const float bvl = bias[n];
#pragma unroll
      for (int r = 0; r < 4; ++r) {
        const int m = m0 + wr * 32 + i * 16 + lrow + r;
        Cf[(size_t)m * 1024 + n] = acc[i][j][r] + bvl;
      }
    }
  }
}

// =====================================================================
extern "C" void kernel_launch(void* const* d_in, const int* in_sizes, int n_in,
                              void* d_out, int out_size, void* d_ws, size_t ws_size,
                              hipStream_t stream)
{
  const float* query = (const float*)d_in[0];
  const float* key   = (const float*)d_in[1];
  const float* value = (const float*)d_in[2];
  const float* rk    = (const float*)d_in[3];
  const float* rv    = (const float*)d_in[4];
  const int*   mask  = (const int*)d_in[5];
  const int*   sep   = (const int*)d_in[6];
  const float* hreg  = (const float*)d_in[7];
  const float* Wq    = (const float*)d_in[8];
  const float* bq    = (const float*)d_in[9];
  const float* Wk    = (const float*)d_in[10];
  const float* bk    = (const float*)d_in[11];
  const float* Wv    = (const float*)d_in[12];
  const float* bv    = (const float*)d_in[13];
  const float* Wo    = (const float*)d_in[14];
  const float* bo    = (const float*)d_in[15];
  const float* hw    = (const float*)d_in[16];
  float* out = (float*)d_out;

  float* ws  = (float*)d_ws;
  bf16* sc16 = (bf16*)ws;                    // 4,194,304 bf16 (8 MB)
  float* xa  = (float*)(sc16 + 4194304);     // 1,048,576 f32
  float* xb2 = xa + 1048576;                 // 1,048,576 f32
  float* gb  = xb2 + 1048576;                //     8,192 f32
  bf16* qb16 = (bf16*)(gb + 8192);           // 1,048,576 bf16
  bf16* kb16 = qb16 + 1048576;               // 1,048,576 bf16
  bf16* vt16 = kb16 + 1048576;               // 1,048,576 bf16
  bf16* pb16 = vt16 + 1048576;               // 4,194,304 bf16
  // conversion buffers: first 4 alias pb16 (dead until relk_sm writes it)
  bf16* qA16 = pb16;
  bf16* kA16 = qA16 + 1048576;
  bf16* vA16 = kA16 + 1048576;
  bf16* Wq16 = vA16 + 1048576;
  bf16* Wk16 = pb16 + 4194304;
  bf16* Wv16 = Wk16 + 1048576;
  bf16* Wo16 = Wv16 + 1048576;

  cvt_bf16<<<dim3(512, 7), 256, 0, stream>>>(query, key, value, Wq, Wk, Wv, Wo,
                                             qA16, kA16, vA16, Wq16, Wk16, Wv16,
                                             Wo16);
  proj3_mfma2<<<dim3(256, 3), 256, 0, stream>>>(qA16, kA16, vA16,
                                                Wq16, Wk16, Wv16, bq, bk, bv,
                                                qb16, kb16, vt16);
  qs_fat<<<dim3(1025), 256, 0, stream>>>(qb16, kb16, sc16,
                                         hw, sep, hreg, gb, out + 1048576);
  relk_sm<<<dim3(1024), 256, 0, stream>>>(qb16, rk, sc16, mask, gb, pb16);
  relv_fat<<<dim3(1280), 256, 0, stream>>>(pb16, vt16, rv, xb2, xa);
  proj_out2<<<dim3(256), 256, 0, stream>>>(xa, xb2, Wo16, bo, out);
}